// Round 14
// baseline (4613.897 us; speedup 1.0000x reference)
//
#include <hip/hip_runtime.h>
#include <hip/hip_cooperative_groups.h>
#include <math.h>

namespace cg = cooperative_groups;

#define N_NODES 50000
#define N_EDGES 800000
#define M_HID   128
#define P_FEAT  256
#define C_OUT   40
#define PWR_ITERS 16
#define FP_ITERS  30
#define KAPPA 0.9f
#define SBLK 256
#define NBK ((N_NODES + 255) / 256)   // 196 histogram blocks

typedef unsigned short u16;
typedef unsigned int   u32;
typedef __attribute__((ext_vector_type(8))) short short8;
typedef __attribute__((ext_vector_type(4))) float f32x4;

// bf16 helpers (RNE)
__device__ inline u16 f2bf(float f) {
    union { float f; u32 u; } c; c.f = f;
    u32 u = c.u + 0x7fffu + ((c.u >> 16) & 1u);
    return (u16)(u >> 16);
}
__device__ inline u32 pack2bf(float lo, float hi) {
    return (u32)f2bf(lo) | ((u32)f2bf(hi) << 16);
}
__device__ inline float bflo(u32 u) { union { u32 u; float f; } c; c.u = u << 16; return c.f; }
__device__ inline float bfhi(u32 u) { union { u32 u; float f; } c; c.u = u & 0xffff0000u; return c.f; }

// ---------------- init ----------------

__global__ void fill_pow(float* buf0, float* ss, int n, float val) {
    int i = blockIdx.x * blockDim.x + threadIdx.x;
    if (i < n) buf0[i] = val;
    if (blockIdx.x == 0 && threadIdx.x < 64) ss[threadIdx.x] = (threadIdx.x == 0) ? 1.f : 0.f;
}

// ---------------- cooperative power iteration on A^T (all iters, one launch) ----

__global__ __launch_bounds__(256) void power_coop(const int* __restrict__ offs,
                                                  const int2* __restrict__ csr,
                                                  const int* __restrict__ perm,
                                                  float* buf0, float* buf1,
                                                  float* ss, int n) {
    cg::grid_group grid = cg::this_grid();
    int t = blockIdx.x * blockDim.x + threadIdx.x;
    int g = t >> 3, q = t & 7;
    int j = -1, lo = 0, hi = 0;
    if (g < n) {
        j = perm[g];
        lo = offs[j]; hi = offs[j + 1];
    }
    __shared__ float ls[4];
    int lane = threadIdx.x & 63, wid = threadIdx.x >> 6;
    float* bufs[2] = {buf0, buf1};
    for (int it = 0; it <= PWR_ITERS; ++it) {
        const float* __restrict__ vin = bufs[it & 1];
        float* __restrict__ vout = bufs[(it + 1) & 1];
        float inv = 1.f / (sqrtf(ss[it]) + 1e-12f);
        float a = 0.f;
        if (g < n) {
            for (int e = lo + q; e < hi; e += 8) {
                int2 c = csr[e];
                a += __int_as_float(c.y) * vin[c.x];
            }
        }
        a += __shfl_xor(a, 1, 64);
        a += __shfl_xor(a, 2, 64);
        a += __shfl_xor(a, 4, 64);
        a *= inv;
        if (g < n && q == 0) vout[j] = a;
        float s = (q == 0 && g < n) ? a * a : 0.f;
        for (int o = 32; o > 0; o >>= 1) s += __shfl_down(s, o, 64);
        if (lane == 0) ls[wid] = s;
        __syncthreads();
        if (threadIdx.x == 0) atomicAdd(&ss[it + 1], ls[0] + ls[1] + ls[2] + ls[3]);
        grid.sync();
    }
}

// ---------------- L1-ball row projection of W -> MFMA B-fragment layout ----------------

__global__ __launch_bounds__(128) void project_w(const float* __restrict__ W,
                                                 const float* __restrict__ rho2,
                                                 u16* __restrict__ Bswz) {
    __shared__ float sa[128];
    __shared__ float ssort[128];
    __shared__ float sc[128];
    __shared__ int cnt2[2];
    int r = blockIdx.x, t = threadIdx.x;
    float radius = KAPPA / sqrtf(*rho2);
    float w0 = W[r * 128 + t];
    float a = fabsf(w0);
    sa[t] = a;
    __syncthreads();
    int rank = 0;
    #pragma unroll 8
    for (int j = 0; j < 128; ++j) {
        float aj = sa[j];
        rank += (aj > a) || (aj == a && j < t);
    }
    ssort[rank] = a;
    __syncthreads();
    sc[t] = ssort[t];
    __syncthreads();
    for (int off = 1; off < 128; off <<= 1) {
        float add = (t >= off) ? sc[t - off] : 0.f;
        __syncthreads();
        sc[t] += add;
        __syncthreads();
    }
    bool flag = ssort[t] * (float)(t + 1) > sc[t] - radius;
    unsigned long long b = __ballot(flag);
    if ((t & 63) == 0) cnt2[t >> 6] = __popcll(b);
    __syncthreads();
    int rho = cnt2[0] + cnt2[1];
    float total = sc[127];
    bool needs = total > radius;
    float theta = (sc[rho - 1] - radius) / (float)rho;
    float o;
    if (needs) {
        float am = a - theta;
        o = (am > 0.f) ? ((w0 > 0.f) ? am : -am) : 0.f;
    } else o = w0;
    int kf = t >> 5, quad = (t >> 3) & 3, jj = t & 7;
    int nt = r >> 4, li = r & 15;
    int l = quad * 16 + li;
    Bswz[((size_t)(kf * 8 + nt) * 64 + l) * 8 + jj] = f2bf(o);
}

// ---------------- Omega_1 -> MFMA B-fragment layout (K=256: kf 0..7) ----------------

__global__ __launch_bounds__(256) void reorder_om(const float* __restrict__ Om,
                                                  u16* __restrict__ Ofrg) {
    int idx = blockIdx.x * 256 + threadIdx.x;   // 128*256
    int r = idx >> 8, k = idx & 255;
    int nt = r >> 4, li = r & 15;
    int kf = k >> 5, sub = (k >> 3) & 3, jj = k & 7;
    int l = sub * 16 + li;
    Ofrg[((size_t)(kf * 8 + nt) * 64 + l) * 8 + jj] = f2bf(Om[idx]);
}

// ---------------- CSR build (by dst only), int2-packed ----------------

__global__ void count_deg(const int* __restrict__ dst, int* deg, int E) {
    int e = blockIdx.x * blockDim.x + threadIdx.x;
    if (e < E) atomicAdd(&deg[dst[e]], 1);
}

__global__ __launch_bounds__(SBLK) void scan_local(const int* __restrict__ deg,
                                                   int* __restrict__ offsets,
                                                   int* __restrict__ bsum, int n1) {
    __shared__ int s[SBLK];
    int i = blockIdx.x * SBLK + threadIdx.x;
    int v = (i < n1 - 1) ? deg[i] : 0;
    s[threadIdx.x] = v;
    __syncthreads();
    for (int o = 1; o < SBLK; o <<= 1) {
        int add = (threadIdx.x >= o) ? s[threadIdx.x - o] : 0;
        __syncthreads();
        s[threadIdx.x] += add;
        __syncthreads();
    }
    if (i < n1) offsets[i] = s[threadIdx.x] - v;   // exclusive
    if (threadIdx.x == SBLK - 1) bsum[blockIdx.x] = s[SBLK - 1];
}

__global__ __launch_bounds__(SBLK) void scan_bsum(const int* __restrict__ bsum,
                                                  int* __restrict__ bbase, int nb) {
    __shared__ int s[SBLK];
    int v = (threadIdx.x < nb) ? bsum[threadIdx.x] : 0;
    s[threadIdx.x] = v;
    __syncthreads();
    for (int o = 1; o < 256; o <<= 1) {
        int add = (threadIdx.x >= o) ? s[threadIdx.x - o] : 0;
        __syncthreads();
        s[threadIdx.x] += add;
        __syncthreads();
    }
    if (threadIdx.x < nb) bbase[threadIdx.x] = s[threadIdx.x] - v;
}

__global__ __launch_bounds__(SBLK) void scan_add(int* __restrict__ offsets,
                                                 int* __restrict__ cursor,
                                                 const int* __restrict__ bbase, int n1) {
    int i = blockIdx.x * SBLK + threadIdx.x;
    if (i < n1) {
        int o = offsets[i] + bbase[blockIdx.x];
        offsets[i] = o;
        if (i < n1 - 1) cursor[i] = o;
    }
}

__global__ void fill_csr(const int* __restrict__ src, const int* __restrict__ dst,
                         const float* __restrict__ w,
                         int* cur_d, int2* csr_d, int E) {
    int e = blockIdx.x * blockDim.x + threadIdx.x;
    if (e < E) {
        int d = dst[e];
        int pd = atomicAdd(&cur_d[d], 1);
        csr_d[pd] = make_int2(src[e], __float_as_int(w[e]));
    }
}

// ---------------- degree-sorted permutation: contention-free block-local sort ----

__global__ __launch_bounds__(256) void bhist(const int* __restrict__ deg,
                                             int* __restrict__ bh, int n) {
    __shared__ int h[256];
    int t = threadIdx.x;
    h[t] = 0;
    __syncthreads();
    int i = blockIdx.x * 256 + t;
    if (i < n) {
        int d = deg[i]; if (d > 255) d = 255;
        atomicAdd(&h[d], 1);
    }
    __syncthreads();
    bh[t * NBK + blockIdx.x] = h[t];
}

__global__ __launch_bounds__(256) void bscatter(const int* __restrict__ deg,
                                                const int* __restrict__ obase,
                                                int* __restrict__ perm, int n) {
    __shared__ int cur[256];
    int t = threadIdx.x;
    cur[t] = obase[t * NBK + blockIdx.x];
    __syncthreads();
    int i = blockIdx.x * 256 + t;
    if (i < n) {
        int d = deg[i]; if (d > 255) d = 255;
        int p = atomicAdd(&cur[d], 1);
        perm[p] = i;
    }
}

__global__ void build_invperm(const int* __restrict__ perm, int* __restrict__ invp, int n) {
    int i = blockIdx.x * blockDim.x + threadIdx.x;
    if (i < n) invp[perm[i]] = i;
}

__global__ void remap_csr(const int2* __restrict__ in, const int* __restrict__ invp,
                          int2* __restrict__ outp, int E) {
    int e = blockIdx.x * blockDim.x + threadIdx.x;
    if (e < E) {
        int2 c = in[e];
        c.x = invp[c.x];
        outp[e] = c;
    }
}

// ---------------- transpose X0 -> bf16, PERMUTED row order ----------------

__global__ void transpose_x0_bf16(const float* __restrict__ X0, const int* __restrict__ invp,
                                  u16* Xb, int n) {
    __shared__ float tile[32][33];
    int jb = blockIdx.x * 32, tb = blockIdx.y * 32;
    int tx = threadIdx.x, ty = threadIdx.y;
    for (int r = 0; r < 32; r += 8) {
        int t = tb + ty + r, j = jb + tx;
        tile[ty + r][tx] = (j < n) ? X0[(size_t)t * n + j] : 0.f;
    }
    __syncthreads();
    for (int r = 0; r < 32; r += 8) {
        int j = jb + ty + r, t = tb + tx;
        if (j < n) Xb[(size_t)invp[j] * 128 + t] = f2bf(tile[tx][ty + r]);
    }
}

// ---------------- gemm_u via MFMA: Utb = F^T @ Om^T (bf16 out) ----------------

__global__ __launch_bounds__(256) void gemm_u_mfma(const float* __restrict__ F,
                                                   const u16* __restrict__ Ofrg,
                                                   u16* __restrict__ Utb, int n) {
    __shared__ u32 As32[64][17];
    int tid = threadIdx.x;
    int w = tid >> 6, l = tid & 63;
    int j0 = blockIdx.x * 64;
    const short8* __restrict__ bfr = (const short8*)Ofrg;
    f32x4 acc[8];
    #pragma unroll
    for (int nt = 0; nt < 8; ++nt) acc[nt] = (f32x4){0.f, 0.f, 0.f, 0.f};
    for (int kf = 0; kf < 8; ++kf) {
        int k0 = kf * 32;
        __syncthreads();
        #pragma unroll
        for (int r = 0; r < 4; ++r) {
            int idx = r * 256 + tid;
            int jj = idx & 63, kk2 = idx >> 6;
            int j = j0 + jj;
            float f0 = 0.f, f1 = 0.f;
            if (j < n) {
                f0 = F[(size_t)(k0 + 2 * kk2) * n + j];
                f1 = F[(size_t)(k0 + 2 * kk2 + 1) * n + j];
            }
            As32[jj][kk2] = pack2bf(f0, f1);
        }
        __syncthreads();
        u32 a0 = As32[w * 16 + (l & 15)][(l >> 4) * 4 + 0];
        u32 a1 = As32[w * 16 + (l & 15)][(l >> 4) * 4 + 1];
        u32 a2 = As32[w * 16 + (l & 15)][(l >> 4) * 4 + 2];
        u32 a3 = As32[w * 16 + (l & 15)][(l >> 4) * 4 + 3];
        short8 a;
        a[0] = (short)(a0 & 0xffff); a[1] = (short)(a0 >> 16);
        a[2] = (short)(a1 & 0xffff); a[3] = (short)(a1 >> 16);
        a[4] = (short)(a2 & 0xffff); a[5] = (short)(a2 >> 16);
        a[6] = (short)(a3 & 0xffff); a[7] = (short)(a3 >> 16);
        #pragma unroll
        for (int nt = 0; nt < 8; ++nt) {
            short8 b = bfr[(kf * 8 + nt) * 64 + l];
            acc[nt] = __builtin_amdgcn_mfma_f32_16x16x32_bf16(a, b, acc[nt], 0, 0, 0);
        }
    }
    int rbase = j0 + w * 16 + (l >> 4) * 4;
    int cbase = l & 15;
    #pragma unroll
    for (int nt = 0; nt < 8; ++nt) {
        int col = nt * 16 + cbase;
        #pragma unroll
        for (int i = 0; i < 4; ++i) {
            int row = rbase + i;
            if (row < n) Utb[(size_t)row * 128 + col] = f2bf(acc[nt][i]);
        }
    }
}

// ---------------- reorder bias into PERM-ORDERED MFMA C-fragment layout ----------------

__global__ __launch_bounds__(256) void reorder_bt(const u16* __restrict__ btr,
                                                  const int* __restrict__ perm,
                                                  uint2* __restrict__ btf, int n) {
    int t = blockIdx.y * 256 + threadIdx.x;   // 0..511
    int idx16 = blockIdx.x;
    int nt = t >> 6, lane = t & 63;
    int r0 = idx16 * 16 + (lane >> 4) * 4;
    int c = nt * 16 + (lane & 15);
    u16 b0 = (r0 + 0 < n) ? btr[(size_t)perm[r0 + 0] * 128 + c] : 0;
    u16 b1 = (r0 + 1 < n) ? btr[(size_t)perm[r0 + 1] * 128 + c] : 0;
    u16 b2 = (r0 + 2 < n) ? btr[(size_t)perm[r0 + 2] * 128 + c] : 0;
    u16 b3 = (r0 + 3 < n) ? btr[(size_t)perm[r0 + 3] * 128 + c] : 0;
    uint2 o;
    o.x = (u32)b0 | ((u32)b1 << 16);
    o.y = (u32)b2 | ((u32)b3 << 16);
    btf[(size_t)(idx16 * 8 + nt) * 64 + lane] = o;
}

// ---------------- spmm bf16 (bias path): Y = X @ A, row-major out (orig order) ----

__global__ __launch_bounds__(256) void spmm_bf16(const int* __restrict__ offsets,
                                                 const int2* __restrict__ csr,
                                                 const int* __restrict__ perm,
                                                 const u16* __restrict__ Xin,
                                                 u16* __restrict__ Yout, int n) {
    int tid = threadIdx.x;
    int wid = tid >> 6, lane = tid & 63;
    int q = lane >> 4, li = lane & 15;
    int jp = blockIdx.x * 16 + wid * 4 + q;
    if (jp >= n) return;
    int j = perm[jp];
    int lo = offsets[j], hi = offsets[j + 1];
    const uint4* __restrict__ X4 = (const uint4*)Xin;
    float a[8] = {};
    int e = lo;
    for (; e + 8 <= hi; e += 8) {
        int2 c[8];
        #pragma unroll
        for (int u = 0; u < 8; ++u) c[u] = csr[e + u];
        uint4 x[8];
        #pragma unroll
        for (int u = 0; u < 8; ++u) x[u] = X4[(size_t)c[u].x * 16 + li];
        #pragma unroll
        for (int u = 0; u < 8; ++u) {
            float w = __int_as_float(c[u].y);
            a[0] += w * bflo(x[u].x); a[1] += w * bfhi(x[u].x);
            a[2] += w * bflo(x[u].y); a[3] += w * bfhi(x[u].y);
            a[4] += w * bflo(x[u].z); a[5] += w * bfhi(x[u].z);
            a[6] += w * bflo(x[u].w); a[7] += w * bfhi(x[u].w);
        }
    }
    for (; e < hi; ++e) {
        int2 c = csr[e];
        float w = __int_as_float(c.y);
        uint4 x = X4[(size_t)c.x * 16 + li];
        a[0] += w * bflo(x.x); a[1] += w * bfhi(x.x);
        a[2] += w * bflo(x.y); a[3] += w * bfhi(x.y);
        a[4] += w * bflo(x.z); a[5] += w * bfhi(x.z);
        a[6] += w * bflo(x.w); a[7] += w * bfhi(x.w);
    }
    uint4 o;
    o.x = pack2bf(a[0], a[1]);
    o.y = pack2bf(a[2], a[3]);
    o.z = pack2bf(a[4], a[5]);
    o.w = pack2bf(a[6], a[7]);
    ((uint4*)Yout)[(size_t)j * 16 + li] = o;
}

// ---------------- fused FP step, PERMUTED X storage ----------------
// X held in perm order: position p = row perm[p]. Gathers via invperm-remapped
// csr; writes block-contiguous (coalesced). Bias btf already perm-ordered.

__global__ __launch_bounds__(512) void fused_fp(const int* __restrict__ offsets,
                                                const int2* __restrict__ csrp,
                                                const int* __restrict__ perm,
                                                const u16* __restrict__ Xin,
                                                const u16* __restrict__ Bswz,
                                                const uint2* __restrict__ btf,
                                                u16* __restrict__ Xout, int n) {
    __shared__ uint4 Ys[32][17];
    int tid = threadIdx.x;

    // ---- gather phase: quarter-wave per permuted row ----
    {
        int qw = tid >> 4, li = tid & 15;
        int jp = blockIdx.x * 32 + qw;
        float a[8] = {};
        if (jp < n) {
            int j = perm[jp];
            int lo = offsets[j], hi = offsets[j + 1];
            const uint4* __restrict__ X4 = (const uint4*)Xin;
            int e = lo;
            for (; e + 8 <= hi; e += 8) {
                int2 c[8];
                #pragma unroll
                for (int u = 0; u < 8; ++u) c[u] = csrp[e + u];
                uint4 x[8];
                #pragma unroll
                for (int u = 0; u < 8; ++u) x[u] = X4[(size_t)c[u].x * 16 + li];
                #pragma unroll
                for (int u = 0; u < 8; ++u) {
                    float w = __int_as_float(c[u].y);
                    a[0] += w * bflo(x[u].x); a[1] += w * bfhi(x[u].x);
                    a[2] += w * bflo(x[u].y); a[3] += w * bfhi(x[u].y);
                    a[4] += w * bflo(x[u].z); a[5] += w * bfhi(x[u].z);
                    a[6] += w * bflo(x[u].w); a[7] += w * bfhi(x[u].w);
                }
            }
            for (; e < hi; ++e) {
                int2 c = csrp[e];
                float w = __int_as_float(c.y);
                uint4 x = X4[(size_t)c.x * 16 + li];
                a[0] += w * bflo(x.x); a[1] += w * bfhi(x.x);
                a[2] += w * bflo(x.y); a[3] += w * bfhi(x.y);
                a[4] += w * bflo(x.z); a[5] += w * bfhi(x.z);
                a[6] += w * bflo(x.w); a[7] += w * bfhi(x.w);
            }
        }
        uint4 o;
        o.x = pack2bf(a[0], a[1]);
        o.y = pack2bf(a[2], a[3]);
        o.z = pack2bf(a[4], a[5]);
        o.w = pack2bf(a[6], a[7]);
        Ys[qw][li] = o;
    }
    __syncthreads();

    // ---- MFMA phase: wave w -> row-group (w&1), col-groups nt = (w>>1)*2 + {0,1} ----
    int w = tid >> 6, l = tid & 63;
    int rg = w & 1;
    int ntb = (w >> 1) * 2;
    f32x4 acc[2];
    acc[0] = (f32x4){0.f, 0.f, 0.f, 0.f};
    acc[1] = (f32x4){0.f, 0.f, 0.f, 0.f};
    const short8* __restrict__ bfr = (const short8*)Bswz;
    #pragma unroll
    for (int kf = 0; kf < 4; ++kf) {
        short8 a = *((const short8*)&Ys[rg * 16 + (l & 15)][kf * 4 + (l >> 4)]);
        #pragma unroll
        for (int t = 0; t < 2; ++t) {
            short8 b = bfr[(kf * 8 + ntb + t) * 64 + l];
            acc[t] = __builtin_amdgcn_mfma_f32_16x16x32_bf16(a, b, acc[t], 0, 0, 0);
        }
    }
    int pidx16 = blockIdx.x * 2 + rg;
    int lrbase = rg * 16 + (l >> 4) * 4;
    int cbase = l & 15;
    #pragma unroll
    for (int t = 0; t < 2; ++t) {
        int nt = ntb + t;
        uint2 bb = btf[(size_t)(pidx16 * 8 + nt) * 64 + l];
        float bi[4] = {bflo(bb.x), bfhi(bb.x), bflo(bb.y), bfhi(bb.y)};
        int col = nt * 16 + cbase;
        #pragma unroll
        for (int i = 0; i < 4; ++i) {
            int jp = blockIdx.x * 32 + lrbase + i;
            if (jp < n) {
                float v = acc[t][i] + bi[i];
                Xout[(size_t)jp * 128 + col] = f2bf(v > 0.f ? v : 0.f);
            }
        }
    }
}

// ---------------- final: normalize rows + H @ Vw^T (permuted bf16 input) ----------------

__global__ __launch_bounds__(256) void final_out(const u16* __restrict__ Xb,
                                                 const int* __restrict__ perm,
                                                 const float* __restrict__ Vw,
                                                 float* __restrict__ out, int n) {
    __shared__ float Vs[40][132];
    int tid = threadIdx.x;
    int jb = blockIdx.x * 64;
    for (int i = tid; i < 40 * 128; i += 256) {
        int c = i >> 7, k = i & 127;
        Vs[c][(k >> 5) * 33 + (k & 31)] = Vw[i];
    }
    int g = tid >> 2, q = tid & 3;
    int jp = jb + g;
    float xs[32];
    float ssq = 0.f;
    if (jp < n) {
        const uint4* X4 = (const uint4*)(Xb + (size_t)jp * 128) + q * 4;
        #pragma unroll
        for (int v = 0; v < 4; ++v) {
            uint4 u = X4[v];
            xs[v * 8 + 0] = bflo(u.x); xs[v * 8 + 1] = bfhi(u.x);
            xs[v * 8 + 2] = bflo(u.y); xs[v * 8 + 3] = bfhi(u.y);
            xs[v * 8 + 4] = bflo(u.z); xs[v * 8 + 5] = bfhi(u.z);
            xs[v * 8 + 6] = bflo(u.w); xs[v * 8 + 7] = bfhi(u.w);
        }
        #pragma unroll
        for (int m = 0; m < 32; ++m) ssq += xs[m] * xs[m];
    } else {
        #pragma unroll
        for (int m = 0; m < 32; ++m) xs[m] = 0.f;
    }
    ssq += __shfl_xor(ssq, 1, 64);
    ssq += __shfl_xor(ssq, 2, 64);
    float inv = 1.f / fmaxf(sqrtf(ssq), 1e-12f);
    #pragma unroll
    for (int m = 0; m < 32; ++m) xs[m] *= inv;
    __syncthreads();
    float pacc[10];
    #pragma unroll
    for (int cc = 0; cc < 10; ++cc) pacc[cc] = 0.f;
    #pragma unroll 1
    for (int c = 0; c < 40; ++c) {
        const float* vrow = &Vs[c][q * 33];
        float acc = 0.f;
        #pragma unroll
        for (int m = 0; m < 32; ++m) acc += xs[m] * vrow[m];
        acc += __shfl_xor(acc, 1, 64);
        acc += __shfl_xor(acc, 2, 64);
        if ((c & 3) == q) pacc[c >> 2] = acc;
    }
    if (jp < n) {
        int j = perm[jp];
        #pragma unroll
        for (int cc = 0; cc < 10; ++cc) {
            int c = cc * 4 + q;
            out[(size_t)j * 40 + c] = pacc[cc];
        }
    }
}

// ---------------- launch ----------------

extern "C" void kernel_launch(void* const* d_in, const int* in_sizes, int n_in,
                              void* d_out, int out_size, void* d_ws, size_t ws_size,
                              hipStream_t stream) {
    const float* F    = (const float*)d_in[0];   // (256, 50000)
    const float* W    = (const float*)d_in[1];   // (128, 128)
    const float* Om   = (const float*)d_in[2];   // (128, 256)
    const float* Vw   = (const float*)d_in[3];   // (40, 128)
    const float* X0   = (const float*)d_in[4];   // (128, 50000)
    const float* ew   = (const float*)d_in[5];   // (E,)
    const int*   esrc = (const int*)d_in[6];
    const int*   edst = (const int*)d_in[7];
    float* out = (float*)d_out;
    (void)in_sizes; (void)n_in; (void)out_size; (void)ws_size;

    char* ws = (char*)d_ws;
    size_t off = 0;
    auto alloc = [&](size_t bytes) -> void* {
        void* p = ws + off;
        off = (off + bytes + 255) & ~(size_t)255;
        return p;
    };
    float* buf0    = (float*)alloc((size_t)N_NODES * 4);
    float* buf1    = (float*)alloc((size_t)N_NODES * 4);
    float* ss      = (float*)alloc(64 * 4);
    int*   deg     = (int*)  alloc((size_t)(N_NODES + 1) * 4);
    int*   offs_d  = (int*)  alloc((size_t)(N_NODES + 1) * 4);
    int*   cur_d   = (int*)  alloc((size_t)N_NODES * 4);
    int*   bsum    = (int*)  alloc(512 * 4);
    int*   bbase   = (int*)  alloc(512 * 4);
    int*   bh      = (int*)  alloc((size_t)(256 * NBK + 1) * 4);
    int*   obase   = (int*)  alloc((size_t)(256 * NBK + 1) * 4);
    int*   ocur    = (int*)  alloc((size_t)(256 * NBK + 1) * 4);
    int*   perm    = (int*)  alloc((size_t)N_NODES * 4);
    int*   invp    = (int*)  alloc((size_t)N_NODES * 4);
    int2*  csr_d   = (int2*) alloc((size_t)N_EDGES * 8);   // by-dst: (src, w)
    int2*  csrp    = (int2*) alloc((size_t)N_EDGES * 8);   // src remapped to perm pos
    u16*   Bswz    = (u16*)  alloc(128 * 128 * 2);
    u16*   Ofrg    = (u16*)  alloc(128 * 256 * 2);
    u16*   btr     = (u16*)  alloc((size_t)N_NODES * 128 * 2);    // bias row-major (orig order)
    uint2* btf     = (uint2*)alloc((size_t)3200 * 512 * 8);       // bias C-frag (perm order)
    u16*   Utb     = (u16*)  alloc((size_t)N_NODES * 128 * 2);
    u16*   Xa      = (u16*)  alloc((size_t)N_NODES * 128 * 2);
    u16*   Xb      = (u16*)  alloc((size_t)N_NODES * 128 * 2);

    hipMemsetAsync(deg, 0, (size_t)(N_NODES + 1) * 4, stream);

    const int n1 = N_NODES + 1;
    const int nb = (n1 + SBLK - 1) / SBLK;   // 196 <= 256

    // ---- CSR build (by dst only) ----
    count_deg<<<(N_EDGES + 255) / 256, 256, 0, stream>>>(edst, deg, N_EDGES);
    scan_local<<<nb, SBLK, 0, stream>>>(deg, offs_d, bsum, n1);
    scan_bsum<<<1, SBLK, 0, stream>>>(bsum, bbase, nb);
    scan_add<<<nb, SBLK, 0, stream>>>(offs_d, cur_d, bbase, n1);
    fill_csr<<<(N_EDGES + 255) / 256, 256, 0, stream>>>(
        esrc, edst, ew, cur_d, csr_d, N_EDGES);

    // ---- degree-sorted permutation (contention-free block-local counting sort) ----
    bhist<<<NBK, 256, 0, stream>>>(deg, bh, N_NODES);
    {
        const int sn1 = 256 * NBK + 1;
        const int snb = (sn1 + SBLK - 1) / SBLK;   // 197 <= 256
        scan_local<<<snb, SBLK, 0, stream>>>(bh, obase, bsum, sn1);
        scan_bsum<<<1, SBLK, 0, stream>>>(bsum, bbase, snb);
        scan_add<<<snb, SBLK, 0, stream>>>(obase, ocur, bbase, sn1);
    }
    bscatter<<<NBK, 256, 0, stream>>>(deg, obase, perm, N_NODES);
    build_invperm<<<(N_NODES + 255) / 256, 256, 0, stream>>>(perm, invp, N_NODES);
    remap_csr<<<(N_EDGES + 255) / 256, 256, 0, stream>>>(csr_d, invp, csrp, N_EDGES);

    // ---- power iteration on A^T: single cooperative kernel ----
    fill_pow<<<(N_NODES + 255) / 256, 256, 0, stream>>>(
        buf0, ss, N_NODES, 1.f / sqrtf((float)N_NODES));
    {
        int n_arg = N_NODES;
        void* args[] = {(void*)&offs_d, (void*)&csr_d, (void*)&perm,
                        (void*)&buf0, (void*)&buf1, (void*)&ss, (void*)&n_arg};
        hipLaunchCooperativeKernel((void*)power_coop,
                                   dim3((8 * N_NODES + 255) / 256), dim3(256),
                                   args, 0, stream);
    }

    // ---- project W (rho^2 = ss[PWR_ITERS+1]) -> Bswz fragments ----
    project_w<<<128, 128, 0, stream>>>(W, ss + PWR_ITERS + 1, Bswz);

    // ---- b = (Omega_1 @ U) @ A : MFMA gemm (bf16) + bf16 spmm -> perm C-frag ----
    reorder_om<<<128, 256, 0, stream>>>(Om, Ofrg);
    gemm_u_mfma<<<(N_NODES + 63) / 64, 256, 0, stream>>>(F, Ofrg, Utb, N_NODES);
    spmm_bf16<<<(N_NODES + 15) / 16, 256, 0, stream>>>(offs_d, csr_d, perm, Utb, btr, N_NODES);
    reorder_bt<<<dim3((N_NODES + 15) / 16, 2), 256, 0, stream>>>(btr, perm, btf, N_NODES);

    // ---- fixed point (fused, permuted X storage) ----
    transpose_x0_bf16<<<dim3((N_NODES + 31) / 32, 4), dim3(32, 8), 0, stream>>>(X0, invp, Xa, N_NODES);
    u16* xb2[2] = {Xa, Xb};
    for (int it = 0; it < FP_ITERS; ++it) {
        fused_fp<<<(N_NODES + 31) / 32, 512, 0, stream>>>(
            offs_d, csrp, perm, xb2[it & 1], Bswz, btf, xb2[(it + 1) & 1], N_NODES);
    }

    // ---- output ----
    final_out<<<(N_NODES + 63) / 64, 256, 0, stream>>>(xb2[FP_ITERS & 1], perm, Vw, out, N_NODES);
}

// Round 15
// 1932.567 us; speedup vs baseline: 2.3874x; 2.3874x over previous
//
#include <hip/hip_runtime.h>
#include <math.h>

#define N_NODES 50000
#define N_EDGES 800000
#define M_HID   128
#define P_FEAT  256
#define C_OUT   40
#define PWR_ITERS 16
#define FP_ITERS  30
#define KAPPA 0.9f
#define SBLK 256
#define NBK ((N_NODES + 255) / 256)   // 196 histogram blocks

typedef unsigned short u16;
typedef unsigned int   u32;
typedef __attribute__((ext_vector_type(8))) short short8;
typedef __attribute__((ext_vector_type(4))) float f32x4;

// bf16 helpers (RNE)
__device__ inline u16 f2bf(float f) {
    union { float f; u32 u; } c; c.f = f;
    u32 u = c.u + 0x7fffu + ((c.u >> 16) & 1u);
    return (u16)(u >> 16);
}
__device__ inline u32 pack2bf(float lo, float hi) {
    return (u32)f2bf(lo) | ((u32)f2bf(hi) << 16);
}
__device__ inline float bflo(u32 u) { union { u32 u; float f; } c; c.u = u << 16; return c.f; }
__device__ inline float bfhi(u32 u) { union { u32 u; float f; } c; c.u = u & 0xffff0000u; return c.f; }

// ---------------- init ----------------

__global__ void fill_pow(float* buf0, float* ss, int n, float val) {
    int i = blockIdx.x * blockDim.x + threadIdx.x;
    if (i < n) buf0[i] = val;
    if (blockIdx.x == 0 && threadIdx.x < 64) ss[threadIdx.x] = (threadIdx.x == 0) ? 1.f : 0.f;
}

// ---------------- power iteration on A^T (same rho): 8 lanes/node, degree-sorted ----

__global__ __launch_bounds__(256) void matvec_norm(const int* __restrict__ offs,
                                                   const int2* __restrict__ csr,
                                                   const int* __restrict__ perm,
                                                   const float* __restrict__ vin,
                                                   const float* __restrict__ n2in,
                                                   float* __restrict__ vout,
                                                   float* n2out, int n) {
    int t = blockIdx.x * blockDim.x + threadIdx.x;
    int g = t >> 3, q = t & 7;
    float inv = 1.f / (sqrtf(*n2in) + 1e-12f);
    float a = 0.f;
    int j = -1;
    if (g < n) {
        j = perm[g];
        int lo = offs[j], hi = offs[j + 1];
        for (int e = lo + q; e < hi; e += 8) {
            int2 c = csr[e];
            a += __int_as_float(c.y) * vin[c.x];
        }
    }
    a += __shfl_xor(a, 1, 64);
    a += __shfl_xor(a, 2, 64);
    a += __shfl_xor(a, 4, 64);
    a *= inv;
    if (g < n && q == 0) vout[j] = a;
    float s = (q == 0 && g < n) ? a * a : 0.f;
    for (int o = 32; o > 0; o >>= 1) s += __shfl_down(s, o, 64);
    __shared__ float ls[4];
    int lane = threadIdx.x & 63, wid = threadIdx.x >> 6;
    if (lane == 0) ls[wid] = s;
    __syncthreads();
    if (threadIdx.x == 0) atomicAdd(n2out, ls[0] + ls[1] + ls[2] + ls[3]);
}

// ---------------- L1-ball row projection of W -> MFMA B-fragment layout ----------------

__global__ __launch_bounds__(128) void project_w(const float* __restrict__ W,
                                                 const float* __restrict__ rho2,
                                                 u16* __restrict__ Bswz) {
    __shared__ float sa[128];
    __shared__ float ssort[128];
    __shared__ float sc[128];
    __shared__ int cnt2[2];
    int r = blockIdx.x, t = threadIdx.x;
    float radius = KAPPA / sqrtf(*rho2);
    float w0 = W[r * 128 + t];
    float a = fabsf(w0);
    sa[t] = a;
    __syncthreads();
    int rank = 0;
    #pragma unroll 8
    for (int j = 0; j < 128; ++j) {
        float aj = sa[j];
        rank += (aj > a) || (aj == a && j < t);
    }
    ssort[rank] = a;
    __syncthreads();
    sc[t] = ssort[t];
    __syncthreads();
    for (int off = 1; off < 128; off <<= 1) {
        float add = (t >= off) ? sc[t - off] : 0.f;
        __syncthreads();
        sc[t] += add;
        __syncthreads();
    }
    bool flag = ssort[t] * (float)(t + 1) > sc[t] - radius;
    unsigned long long b = __ballot(flag);
    if ((t & 63) == 0) cnt2[t >> 6] = __popcll(b);
    __syncthreads();
    int rho = cnt2[0] + cnt2[1];
    float total = sc[127];
    bool needs = total > radius;
    float theta = (sc[rho - 1] - radius) / (float)rho;
    float o;
    if (needs) {
        float am = a - theta;
        o = (am > 0.f) ? ((w0 > 0.f) ? am : -am) : 0.f;
    } else o = w0;
    int kf = t >> 5, quad = (t >> 3) & 3, jj = t & 7;
    int nt = r >> 4, li = r & 15;
    int l = quad * 16 + li;
    Bswz[((size_t)(kf * 8 + nt) * 64 + l) * 8 + jj] = f2bf(o);
}

// ---------------- Omega_1 -> MFMA B-fragment layout (K=256: kf 0..7) ----------------

__global__ __launch_bounds__(256) void reorder_om(const float* __restrict__ Om,
                                                  u16* __restrict__ Ofrg) {
    int idx = blockIdx.x * 256 + threadIdx.x;   // 128*256
    int r = idx >> 8, k = idx & 255;
    int nt = r >> 4, li = r & 15;
    int kf = k >> 5, sub = (k >> 3) & 3, jj = k & 7;
    int l = sub * 16 + li;
    Ofrg[((size_t)(kf * 8 + nt) * 64 + l) * 8 + jj] = f2bf(Om[idx]);
}

// ---------------- CSR build (by dst only), int2-packed ----------------

__global__ void count_deg(const int* __restrict__ dst, int* deg, int E) {
    int e = blockIdx.x * blockDim.x + threadIdx.x;
    if (e < E) atomicAdd(&deg[dst[e]], 1);
}

__global__ __launch_bounds__(SBLK) void scan_local(const int* __restrict__ deg,
                                                   int* __restrict__ offsets,
                                                   int* __restrict__ bsum, int n1) {
    __shared__ int s[SBLK];
    int i = blockIdx.x * SBLK + threadIdx.x;
    int v = (i < n1 - 1) ? deg[i] : 0;
    s[threadIdx.x] = v;
    __syncthreads();
    for (int o = 1; o < SBLK; o <<= 1) {
        int add = (threadIdx.x >= o) ? s[threadIdx.x - o] : 0;
        __syncthreads();
        s[threadIdx.x] += add;
        __syncthreads();
    }
    if (i < n1) offsets[i] = s[threadIdx.x] - v;   // exclusive
    if (threadIdx.x == SBLK - 1) bsum[blockIdx.x] = s[SBLK - 1];
}

__global__ __launch_bounds__(SBLK) void scan_bsum(const int* __restrict__ bsum,
                                                  int* __restrict__ bbase, int nb) {
    __shared__ int s[SBLK];
    int v = (threadIdx.x < nb) ? bsum[threadIdx.x] : 0;
    s[threadIdx.x] = v;
    __syncthreads();
    for (int o = 1; o < 256; o <<= 1) {
        int add = (threadIdx.x >= o) ? s[threadIdx.x - o] : 0;
        __syncthreads();
        s[threadIdx.x] += add;
        __syncthreads();
    }
    if (threadIdx.x < nb) bbase[threadIdx.x] = s[threadIdx.x] - v;
}

__global__ __launch_bounds__(SBLK) void scan_add(int* __restrict__ offsets,
                                                 int* __restrict__ cursor,
                                                 const int* __restrict__ bbase, int n1) {
    int i = blockIdx.x * SBLK + threadIdx.x;
    if (i < n1) {
        int o = offsets[i] + bbase[blockIdx.x];
        offsets[i] = o;
        if (i < n1 - 1) cursor[i] = o;
    }
}

__global__ void fill_csr(const int* __restrict__ src, const int* __restrict__ dst,
                         const float* __restrict__ w,
                         int* cur_d, int2* csr_d, int E) {
    int e = blockIdx.x * blockDim.x + threadIdx.x;
    if (e < E) {
        int d = dst[e];
        int pd = atomicAdd(&cur_d[d], 1);
        csr_d[pd] = make_int2(src[e], __float_as_int(w[e]));
    }
}

// ---------------- degree-sorted permutation: contention-free block-local sort ----

__global__ __launch_bounds__(256) void bhist(const int* __restrict__ deg,
                                             int* __restrict__ bh, int n) {
    __shared__ int h[256];
    int t = threadIdx.x;
    h[t] = 0;
    __syncthreads();
    int i = blockIdx.x * 256 + t;
    if (i < n) {
        int d = deg[i]; if (d > 255) d = 255;
        atomicAdd(&h[d], 1);
    }
    __syncthreads();
    bh[t * NBK + blockIdx.x] = h[t];
}

__global__ __launch_bounds__(256) void bscatter(const int* __restrict__ deg,
                                                const int* __restrict__ obase,
                                                int* __restrict__ perm, int n) {
    __shared__ int cur[256];
    int t = threadIdx.x;
    cur[t] = obase[t * NBK + blockIdx.x];
    __syncthreads();
    int i = blockIdx.x * 256 + t;
    if (i < n) {
        int d = deg[i]; if (d > 255) d = 255;
        int p = atomicAdd(&cur[d], 1);
        perm[p] = i;
    }
}

__global__ void build_invperm(const int* __restrict__ perm, int* __restrict__ invp, int n) {
    int i = blockIdx.x * blockDim.x + threadIdx.x;
    if (i < n) invp[perm[i]] = i;
}

__global__ void remap_csr(const int2* __restrict__ in, const int* __restrict__ invp,
                          int2* __restrict__ outp, int E) {
    int e = blockIdx.x * blockDim.x + threadIdx.x;
    if (e < E) {
        int2 c = in[e];
        c.x = invp[c.x];
        outp[e] = c;
    }
}

// ---------------- transpose X0 -> bf16, PERMUTED row order ----------------

__global__ void transpose_x0_bf16(const float* __restrict__ X0, const int* __restrict__ invp,
                                  u16* Xb, int n) {
    __shared__ float tile[32][33];
    int jb = blockIdx.x * 32, tb = blockIdx.y * 32;
    int tx = threadIdx.x, ty = threadIdx.y;
    for (int r = 0; r < 32; r += 8) {
        int t = tb + ty + r, j = jb + tx;
        tile[ty + r][tx] = (j < n) ? X0[(size_t)t * n + j] : 0.f;
    }
    __syncthreads();
    for (int r = 0; r < 32; r += 8) {
        int j = jb + ty + r, t = tb + tx;
        if (j < n) Xb[(size_t)invp[j] * 128 + t] = f2bf(tile[tx][ty + r]);
    }
}

// ---------------- gemm_u via MFMA: Utb = F^T @ Om^T (bf16 out) ----------------

__global__ __launch_bounds__(256) void gemm_u_mfma(const float* __restrict__ F,
                                                   const u16* __restrict__ Ofrg,
                                                   u16* __restrict__ Utb, int n) {
    __shared__ u32 As32[64][17];
    int tid = threadIdx.x;
    int w = tid >> 6, l = tid & 63;
    int j0 = blockIdx.x * 64;
    const short8* __restrict__ bfr = (const short8*)Ofrg;
    f32x4 acc[8];
    #pragma unroll
    for (int nt = 0; nt < 8; ++nt) acc[nt] = (f32x4){0.f, 0.f, 0.f, 0.f};
    for (int kf = 0; kf < 8; ++kf) {
        int k0 = kf * 32;
        __syncthreads();
        #pragma unroll
        for (int r = 0; r < 4; ++r) {
            int idx = r * 256 + tid;
            int jj = idx & 63, kk2 = idx >> 6;
            int j = j0 + jj;
            float f0 = 0.f, f1 = 0.f;
            if (j < n) {
                f0 = F[(size_t)(k0 + 2 * kk2) * n + j];
                f1 = F[(size_t)(k0 + 2 * kk2 + 1) * n + j];
            }
            As32[jj][kk2] = pack2bf(f0, f1);
        }
        __syncthreads();
        u32 a0 = As32[w * 16 + (l & 15)][(l >> 4) * 4 + 0];
        u32 a1 = As32[w * 16 + (l & 15)][(l >> 4) * 4 + 1];
        u32 a2 = As32[w * 16 + (l & 15)][(l >> 4) * 4 + 2];
        u32 a3 = As32[w * 16 + (l & 15)][(l >> 4) * 4 + 3];
        short8 a;
        a[0] = (short)(a0 & 0xffff); a[1] = (short)(a0 >> 16);
        a[2] = (short)(a1 & 0xffff); a[3] = (short)(a1 >> 16);
        a[4] = (short)(a2 & 0xffff); a[5] = (short)(a2 >> 16);
        a[6] = (short)(a3 & 0xffff); a[7] = (short)(a3 >> 16);
        #pragma unroll
        for (int nt = 0; nt < 8; ++nt) {
            short8 b = bfr[(kf * 8 + nt) * 64 + l];
            acc[nt] = __builtin_amdgcn_mfma_f32_16x16x32_bf16(a, b, acc[nt], 0, 0, 0);
        }
    }
    int rbase = j0 + w * 16 + (l >> 4) * 4;
    int cbase = l & 15;
    #pragma unroll
    for (int nt = 0; nt < 8; ++nt) {
        int col = nt * 16 + cbase;
        #pragma unroll
        for (int i = 0; i < 4; ++i) {
            int row = rbase + i;
            if (row < n) Utb[(size_t)row * 128 + col] = f2bf(acc[nt][i]);
        }
    }
}

// ---------------- reorder bias into PERM-ORDERED MFMA C-fragment layout ----------------

__global__ __launch_bounds__(256) void reorder_bt(const u16* __restrict__ btr,
                                                  const int* __restrict__ perm,
                                                  uint2* __restrict__ btf, int n) {
    int t = blockIdx.y * 256 + threadIdx.x;   // 0..511
    int idx16 = blockIdx.x;
    int nt = t >> 6, lane = t & 63;
    int r0 = idx16 * 16 + (lane >> 4) * 4;
    int c = nt * 16 + (lane & 15);
    u16 b0 = (r0 + 0 < n) ? btr[(size_t)perm[r0 + 0] * 128 + c] : 0;
    u16 b1 = (r0 + 1 < n) ? btr[(size_t)perm[r0 + 1] * 128 + c] : 0;
    u16 b2 = (r0 + 2 < n) ? btr[(size_t)perm[r0 + 2] * 128 + c] : 0;
    u16 b3 = (r0 + 3 < n) ? btr[(size_t)perm[r0 + 3] * 128 + c] : 0;
    uint2 o;
    o.x = (u32)b0 | ((u32)b1 << 16);
    o.y = (u32)b2 | ((u32)b3 << 16);
    btf[(size_t)(idx16 * 8 + nt) * 64 + lane] = o;
}

// ---------------- spmm bf16 (bias path): Y = X @ A, row-major out (orig order) ----

__global__ __launch_bounds__(256) void spmm_bf16(const int* __restrict__ offsets,
                                                 const int2* __restrict__ csr,
                                                 const int* __restrict__ perm,
                                                 const u16* __restrict__ Xin,
                                                 u16* __restrict__ Yout, int n) {
    int tid = threadIdx.x;
    int wid = tid >> 6, lane = tid & 63;
    int q = lane >> 4, li = lane & 15;
    int jp = blockIdx.x * 16 + wid * 4 + q;
    if (jp >= n) return;
    int j = perm[jp];
    int lo = offsets[j], hi = offsets[j + 1];
    const uint4* __restrict__ X4 = (const uint4*)Xin;
    float a[8] = {};
    int e = lo;
    for (; e + 8 <= hi; e += 8) {
        int2 c[8];
        #pragma unroll
        for (int u = 0; u < 8; ++u) c[u] = csr[e + u];
        uint4 x[8];
        #pragma unroll
        for (int u = 0; u < 8; ++u) x[u] = X4[(size_t)c[u].x * 16 + li];
        #pragma unroll
        for (int u = 0; u < 8; ++u) {
            float w = __int_as_float(c[u].y);
            a[0] += w * bflo(x[u].x); a[1] += w * bfhi(x[u].x);
            a[2] += w * bflo(x[u].y); a[3] += w * bfhi(x[u].y);
            a[4] += w * bflo(x[u].z); a[5] += w * bfhi(x[u].z);
            a[6] += w * bflo(x[u].w); a[7] += w * bfhi(x[u].w);
        }
    }
    for (; e < hi; ++e) {
        int2 c = csr[e];
        float w = __int_as_float(c.y);
        uint4 x = X4[(size_t)c.x * 16 + li];
        a[0] += w * bflo(x.x); a[1] += w * bfhi(x.x);
        a[2] += w * bflo(x.y); a[3] += w * bfhi(x.y);
        a[4] += w * bflo(x.z); a[5] += w * bfhi(x.z);
        a[6] += w * bflo(x.w); a[7] += w * bfhi(x.w);
    }
    uint4 o;
    o.x = pack2bf(a[0], a[1]);
    o.y = pack2bf(a[2], a[3]);
    o.z = pack2bf(a[4], a[5]);
    o.w = pack2bf(a[6], a[7]);
    ((uint4*)Yout)[(size_t)j * 16 + li] = o;
}

// ---------------- fused FP step, PERMUTED X storage ----------------

__global__ __launch_bounds__(512) void fused_fp(const int* __restrict__ offsets,
                                                const int2* __restrict__ csrp,
                                                const int* __restrict__ perm,
                                                const u16* __restrict__ Xin,
                                                const u16* __restrict__ Bswz,
                                                const uint2* __restrict__ btf,
                                                u16* __restrict__ Xout, int n) {
    __shared__ uint4 Ys[32][17];
    int tid = threadIdx.x;

    // ---- gather phase: quarter-wave per permuted row ----
    {
        int qw = tid >> 4, li = tid & 15;
        int jp = blockIdx.x * 32 + qw;
        float a[8] = {};
        if (jp < n) {
            int j = perm[jp];
            int lo = offsets[j], hi = offsets[j + 1];
            const uint4* __restrict__ X4 = (const uint4*)Xin;
            int e = lo;
            for (; e + 8 <= hi; e += 8) {
                int2 c[8];
                #pragma unroll
                for (int u = 0; u < 8; ++u) c[u] = csrp[e + u];
                uint4 x[8];
                #pragma unroll
                for (int u = 0; u < 8; ++u) x[u] = X4[(size_t)c[u].x * 16 + li];
                #pragma unroll
                for (int u = 0; u < 8; ++u) {
                    float w = __int_as_float(c[u].y);
                    a[0] += w * bflo(x[u].x); a[1] += w * bfhi(x[u].x);
                    a[2] += w * bflo(x[u].y); a[3] += w * bfhi(x[u].y);
                    a[4] += w * bflo(x[u].z); a[5] += w * bfhi(x[u].z);
                    a[6] += w * bflo(x[u].w); a[7] += w * bfhi(x[u].w);
                }
            }
            for (; e < hi; ++e) {
                int2 c = csrp[e];
                float w = __int_as_float(c.y);
                uint4 x = X4[(size_t)c.x * 16 + li];
                a[0] += w * bflo(x.x); a[1] += w * bfhi(x.x);
                a[2] += w * bflo(x.y); a[3] += w * bfhi(x.y);
                a[4] += w * bflo(x.z); a[5] += w * bfhi(x.z);
                a[6] += w * bflo(x.w); a[7] += w * bfhi(x.w);
            }
        }
        uint4 o;
        o.x = pack2bf(a[0], a[1]);
        o.y = pack2bf(a[2], a[3]);
        o.z = pack2bf(a[4], a[5]);
        o.w = pack2bf(a[6], a[7]);
        Ys[qw][li] = o;
    }
    __syncthreads();

    // ---- MFMA phase ----
    int w = tid >> 6, l = tid & 63;
    int rg = w & 1;
    int ntb = (w >> 1) * 2;
    f32x4 acc[2];
    acc[0] = (f32x4){0.f, 0.f, 0.f, 0.f};
    acc[1] = (f32x4){0.f, 0.f, 0.f, 0.f};
    const short8* __restrict__ bfr = (const short8*)Bswz;
    #pragma unroll
    for (int kf = 0; kf < 4; ++kf) {
        short8 a = *((const short8*)&Ys[rg * 16 + (l & 15)][kf * 4 + (l >> 4)]);
        #pragma unroll
        for (int t = 0; t < 2; ++t) {
            short8 b = bfr[(kf * 8 + ntb + t) * 64 + l];
            acc[t] = __builtin_amdgcn_mfma_f32_16x16x32_bf16(a, b, acc[t], 0, 0, 0);
        }
    }
    int pidx16 = blockIdx.x * 2 + rg;
    int lrbase = rg * 16 + (l >> 4) * 4;
    int cbase = l & 15;
    #pragma unroll
    for (int t = 0; t < 2; ++t) {
        int nt = ntb + t;
        uint2 bb = btf[(size_t)(pidx16 * 8 + nt) * 64 + l];
        float bi[4] = {bflo(bb.x), bfhi(bb.x), bflo(bb.y), bfhi(bb.y)};
        int col = nt * 16 + cbase;
        #pragma unroll
        for (int i = 0; i < 4; ++i) {
            int jp = blockIdx.x * 32 + lrbase + i;
            if (jp < n) {
                float v = acc[t][i] + bi[i];
                Xout[(size_t)jp * 128 + col] = f2bf(v > 0.f ? v : 0.f);
            }
        }
    }
}

// ---------------- final: normalize rows + H @ Vw^T (permuted bf16 input) ----------------

__global__ __launch_bounds__(256) void final_out(const u16* __restrict__ Xb,
                                                 const int* __restrict__ perm,
                                                 const float* __restrict__ Vw,
                                                 float* __restrict__ out, int n) {
    __shared__ float Vs[40][132];
    int tid = threadIdx.x;
    int jb = blockIdx.x * 64;
    for (int i = tid; i < 40 * 128; i += 256) {
        int c = i >> 7, k = i & 127;
        Vs[c][(k >> 5) * 33 + (k & 31)] = Vw[i];
    }
    int g = tid >> 2, q = tid & 3;
    int jp = jb + g;
    float xs[32];
    float ssq = 0.f;
    if (jp < n) {
        const uint4* X4 = (const uint4*)(Xb + (size_t)jp * 128) + q * 4;
        #pragma unroll
        for (int v = 0; v < 4; ++v) {
            uint4 u = X4[v];
            xs[v * 8 + 0] = bflo(u.x); xs[v * 8 + 1] = bfhi(u.x);
            xs[v * 8 + 2] = bflo(u.y); xs[v * 8 + 3] = bfhi(u.y);
            xs[v * 8 + 4] = bflo(u.z); xs[v * 8 + 5] = bfhi(u.z);
            xs[v * 8 + 6] = bflo(u.w); xs[v * 8 + 7] = bfhi(u.w);
        }
        #pragma unroll
        for (int m = 0; m < 32; ++m) ssq += xs[m] * xs[m];
    } else {
        #pragma unroll
        for (int m = 0; m < 32; ++m) xs[m] = 0.f;
    }
    ssq += __shfl_xor(ssq, 1, 64);
    ssq += __shfl_xor(ssq, 2, 64);
    float inv = 1.f / fmaxf(sqrtf(ssq), 1e-12f);
    #pragma unroll
    for (int m = 0; m < 32; ++m) xs[m] *= inv;
    __syncthreads();
    float pacc[10];
    #pragma unroll
    for (int cc = 0; cc < 10; ++cc) pacc[cc] = 0.f;
    #pragma unroll 1
    for (int c = 0; c < 40; ++c) {
        const float* vrow = &Vs[c][q * 33];
        float acc = 0.f;
        #pragma unroll
        for (int m = 0; m < 32; ++m) acc += xs[m] * vrow[m];
        acc += __shfl_xor(acc, 1, 64);
        acc += __shfl_xor(acc, 2, 64);
        if ((c & 3) == q) pacc[c >> 2] = acc;
    }
    if (jp < n) {
        int j = perm[jp];
        #pragma unroll
        for (int cc = 0; cc < 10; ++cc) {
            int c = cc * 4 + q;
            out[(size_t)j * 40 + c] = pacc[cc];
        }
    }
}

// ---------------- launch ----------------

extern "C" void kernel_launch(void* const* d_in, const int* in_sizes, int n_in,
                              void* d_out, int out_size, void* d_ws, size_t ws_size,
                              hipStream_t stream) {
    const float* F    = (const float*)d_in[0];   // (256, 50000)
    const float* W    = (const float*)d_in[1];   // (128, 128)
    const float* Om   = (const float*)d_in[2];   // (128, 256)
    const float* Vw   = (const float*)d_in[3];   // (40, 128)
    const float* X0   = (const float*)d_in[4];   // (128, 50000)
    const float* ew   = (const float*)d_in[5];   // (E,)
    const int*   esrc = (const int*)d_in[6];
    const int*   edst = (const int*)d_in[7];
    float* out = (float*)d_out;
    (void)in_sizes; (void)n_in; (void)out_size; (void)ws_size;

    char* ws = (char*)d_ws;
    size_t off = 0;
    auto alloc = [&](size_t bytes) -> void* {
        void* p = ws + off;
        off = (off + bytes + 255) & ~(size_t)255;
        return p;
    };
    float* buf0    = (float*)alloc((size_t)N_NODES * 4);
    float* buf1    = (float*)alloc((size_t)N_NODES * 4);
    float* ss      = (float*)alloc(64 * 4);
    int*   deg     = (int*)  alloc((size_t)(N_NODES + 1) * 4);
    int*   offs_d  = (int*)  alloc((size_t)(N_NODES + 1) * 4);
    int*   cur_d   = (int*)  alloc((size_t)N_NODES * 4);
    int*   bsum    = (int*)  alloc(512 * 4);
    int*   bbase   = (int*)  alloc(512 * 4);
    int*   bh      = (int*)  alloc((size_t)(256 * NBK + 1) * 4);
    int*   obase   = (int*)  alloc((size_t)(256 * NBK + 1) * 4);
    int*   ocur    = (int*)  alloc((size_t)(256 * NBK + 1) * 4);
    int*   perm    = (int*)  alloc((size_t)N_NODES * 4);
    int*   invp    = (int*)  alloc((size_t)N_NODES * 4);
    int2*  csr_d   = (int2*) alloc((size_t)N_EDGES * 8);   // by-dst: (src, w)
    int2*  csrp    = (int2*) alloc((size_t)N_EDGES * 8);   // src remapped to perm pos
    u16*   Bswz    = (u16*)  alloc(128 * 128 * 2);
    u16*   Ofrg    = (u16*)  alloc(128 * 256 * 2);
    u16*   btr     = (u16*)  alloc((size_t)N_NODES * 128 * 2);    // bias row-major (orig order)
    uint2* btf     = (uint2*)alloc((size_t)3200 * 512 * 8);       // bias C-frag (perm order)
    u16*   Utb     = (u16*)  alloc((size_t)N_NODES * 128 * 2);
    u16*   Xa      = (u16*)  alloc((size_t)N_NODES * 128 * 2);
    u16*   Xb      = (u16*)  alloc((size_t)N_NODES * 128 * 2);

    hipMemsetAsync(deg, 0, (size_t)(N_NODES + 1) * 4, stream);

    const int n1 = N_NODES + 1;
    const int nb = (n1 + SBLK - 1) / SBLK;   // 196 <= 256

    // ---- CSR build (by dst only) ----
    count_deg<<<(N_EDGES + 255) / 256, 256, 0, stream>>>(edst, deg, N_EDGES);
    scan_local<<<nb, SBLK, 0, stream>>>(deg, offs_d, bsum, n1);
    scan_bsum<<<1, SBLK, 0, stream>>>(bsum, bbase, nb);
    scan_add<<<nb, SBLK, 0, stream>>>(offs_d, cur_d, bbase, n1);
    fill_csr<<<(N_EDGES + 255) / 256, 256, 0, stream>>>(
        esrc, edst, ew, cur_d, csr_d, N_EDGES);

    // ---- degree-sorted permutation (contention-free block-local counting sort) ----
    bhist<<<NBK, 256, 0, stream>>>(deg, bh, N_NODES);
    {
        const int sn1 = 256 * NBK + 1;
        const int snb = (sn1 + SBLK - 1) / SBLK;   // 197 <= 256
        scan_local<<<snb, SBLK, 0, stream>>>(bh, obase, bsum, sn1);
        scan_bsum<<<1, SBLK, 0, stream>>>(bsum, bbase, snb);
        scan_add<<<snb, SBLK, 0, stream>>>(obase, ocur, bbase, sn1);
    }
    bscatter<<<NBK, 256, 0, stream>>>(deg, obase, perm, N_NODES);
    build_invperm<<<(N_NODES + 255) / 256, 256, 0, stream>>>(perm, invp, N_NODES);
    remap_csr<<<(N_EDGES + 255) / 256, 256, 0, stream>>>(csr_d, invp, csrp, N_EDGES);

    // ---- power iteration on A^T: discrete launches (coop grid.sync was 20x slower) ----
    fill_pow<<<(N_NODES + 255) / 256, 256, 0, stream>>>(
        buf0, ss, N_NODES, 1.f / sqrtf((float)N_NODES));
    float* bufs[2] = {buf0, buf1};
    for (int it = 0; it <= PWR_ITERS; ++it) {
        matvec_norm<<<(8 * N_NODES + 255) / 256, 256, 0, stream>>>(
            offs_d, csr_d, perm, bufs[it & 1], ss + it,
            bufs[(it + 1) & 1], ss + it + 1, N_NODES);
    }

    // ---- project W (rho^2 = ss[PWR_ITERS+1]) -> Bswz fragments ----
    project_w<<<128, 128, 0, stream>>>(W, ss + PWR_ITERS + 1, Bswz);

    // ---- b = (Omega_1 @ U) @ A : MFMA gemm (bf16) + bf16 spmm -> perm C-frag ----
    reorder_om<<<128, 256, 0, stream>>>(Om, Ofrg);
    gemm_u_mfma<<<(N_NODES + 63) / 64, 256, 0, stream>>>(F, Ofrg, Utb, N_NODES);
    spmm_bf16<<<(N_NODES + 15) / 16, 256, 0, stream>>>(offs_d, csr_d, perm, Utb, btr, N_NODES);
    reorder_bt<<<dim3((N_NODES + 15) / 16, 2), 256, 0, stream>>>(btr, perm, btf, N_NODES);

    // ---- fixed point (fused, permuted X storage) ----
    transpose_x0_bf16<<<dim3((N_NODES + 31) / 32, 4), dim3(32, 8), 0, stream>>>(X0, invp, Xa, N_NODES);
    u16* xb2[2] = {Xa, Xb};
    for (int it = 0; it < FP_ITERS; ++it) {
        fused_fp<<<(N_NODES + 31) / 32, 512, 0, stream>>>(
            offs_d, csrp, perm, xb2[it & 1], Bswz, btf, xb2[(it + 1) & 1], N_NODES);
    }

    // ---- output ----
    final_out<<<(N_NODES + 63) / 64, 256, 0, stream>>>(xb2[FP_ITERS & 1], perm, Vw, out, N_NODES);
}

// Round 16
// 1786.609 us; speedup vs baseline: 2.5825x; 1.0817x over previous
//
#include <hip/hip_runtime.h>
#include <math.h>

#define N_NODES 50000
#define N_EDGES 800000
#define M_HID   128
#define P_FEAT  256
#define C_OUT   40
#define PWR_ITERS 12
#define FP_ITERS  30
#define KAPPA 0.9f
#define SBLK 256
#define NBK ((N_NODES + 255) / 256)   // 196 histogram blocks

typedef unsigned short u16;
typedef unsigned int   u32;
typedef __attribute__((ext_vector_type(8))) short short8;
typedef __attribute__((ext_vector_type(4))) float f32x4;

// bf16 helpers (RNE)
__device__ inline u16 f2bf(float f) {
    union { float f; u32 u; } c; c.f = f;
    u32 u = c.u + 0x7fffu + ((c.u >> 16) & 1u);
    return (u16)(u >> 16);
}
__device__ inline u32 pack2bf(float lo, float hi) {
    return (u32)f2bf(lo) | ((u32)f2bf(hi) << 16);
}
__device__ inline float bflo(u32 u) { union { u32 u; float f; } c; c.u = u << 16; return c.f; }
__device__ inline float bfhi(u32 u) { union { u32 u; float f; } c; c.u = u & 0xffff0000u; return c.f; }

// ---------------- init ----------------

__global__ void fill_pow(float* buf0, float* ss, int n, float val) {
    int i = blockIdx.x * blockDim.x + threadIdx.x;
    if (i < n) buf0[i] = val;
    if (blockIdx.x == 0 && threadIdx.x < 64) ss[threadIdx.x] = (threadIdx.x == 0) ? 1.f : 0.f;
}

// ---------------- power iteration on A^T, fully perm-space ----------------
// v stored positionally (perm space); csrp.x are perm positions. vout write coalesced.

__global__ __launch_bounds__(256) void matvec_norm(const int2* __restrict__ rowrange,
                                                   const int2* __restrict__ csrp,
                                                   const float* __restrict__ vin,
                                                   const float* __restrict__ n2in,
                                                   float* __restrict__ vout,
                                                   float* n2out, int n) {
    int t = blockIdx.x * blockDim.x + threadIdx.x;
    int g = t >> 3, q = t & 7;
    float inv = 1.f / (sqrtf(*n2in) + 1e-12f);
    float a = 0.f;
    if (g < n) {
        int2 rr = rowrange[g];
        for (int e = rr.x + q; e < rr.y; e += 8) {
            int2 c = csrp[e];
            a += __int_as_float(c.y) * vin[c.x];
        }
    }
    a += __shfl_xor(a, 1, 64);
    a += __shfl_xor(a, 2, 64);
    a += __shfl_xor(a, 4, 64);
    a *= inv;
    if (g < n && q == 0) vout[g] = a;
    float s = (q == 0 && g < n) ? a * a : 0.f;
    for (int o = 32; o > 0; o >>= 1) s += __shfl_down(s, o, 64);
    __shared__ float ls[4];
    int lane = threadIdx.x & 63, wid = threadIdx.x >> 6;
    if (lane == 0) ls[wid] = s;
    __syncthreads();
    if (threadIdx.x == 0) atomicAdd(n2out, ls[0] + ls[1] + ls[2] + ls[3]);
}

// ---------------- L1-ball row projection of W -> MFMA B-fragment layout ----------------

__global__ __launch_bounds__(128) void project_w(const float* __restrict__ W,
                                                 const float* __restrict__ rho2,
                                                 u16* __restrict__ Bswz) {
    __shared__ float sa[128];
    __shared__ float ssort[128];
    __shared__ float sc[128];
    __shared__ int cnt2[2];
    int r = blockIdx.x, t = threadIdx.x;
    float radius = KAPPA / sqrtf(*rho2);
    float w0 = W[r * 128 + t];
    float a = fabsf(w0);
    sa[t] = a;
    __syncthreads();
    int rank = 0;
    #pragma unroll 8
    for (int j = 0; j < 128; ++j) {
        float aj = sa[j];
        rank += (aj > a) || (aj == a && j < t);
    }
    ssort[rank] = a;
    __syncthreads();
    sc[t] = ssort[t];
    __syncthreads();
    for (int off = 1; off < 128; off <<= 1) {
        float add = (t >= off) ? sc[t - off] : 0.f;
        __syncthreads();
        sc[t] += add;
        __syncthreads();
    }
    bool flag = ssort[t] * (float)(t + 1) > sc[t] - radius;
    unsigned long long b = __ballot(flag);
    if ((t & 63) == 0) cnt2[t >> 6] = __popcll(b);
    __syncthreads();
    int rho = cnt2[0] + cnt2[1];
    float total = sc[127];
    bool needs = total > radius;
    float theta = (sc[rho - 1] - radius) / (float)rho;
    float o;
    if (needs) {
        float am = a - theta;
        o = (am > 0.f) ? ((w0 > 0.f) ? am : -am) : 0.f;
    } else o = w0;
    int kf = t >> 5, quad = (t >> 3) & 3, jj = t & 7;
    int nt = r >> 4, li = r & 15;
    int l = quad * 16 + li;
    Bswz[((size_t)(kf * 8 + nt) * 64 + l) * 8 + jj] = f2bf(o);
}

// ---------------- Omega_1 -> MFMA B-fragment layout (K=256: kf 0..7) ----------------

__global__ __launch_bounds__(256) void reorder_om(const float* __restrict__ Om,
                                                  u16* __restrict__ Ofrg) {
    int idx = blockIdx.x * 256 + threadIdx.x;   // 128*256
    int r = idx >> 8, k = idx & 255;
    int nt = r >> 4, li = r & 15;
    int kf = k >> 5, sub = (k >> 3) & 3, jj = k & 7;
    int l = sub * 16 + li;
    Ofrg[((size_t)(kf * 8 + nt) * 64 + l) * 8 + jj] = f2bf(Om[idx]);
}

// ---------------- CSR build, PERM-SPACE src indices ----------------

__global__ void count_deg(const int* __restrict__ dst, int* deg, int E) {
    int e = blockIdx.x * blockDim.x + threadIdx.x;
    if (e < E) atomicAdd(&deg[dst[e]], 1);
}

__global__ __launch_bounds__(SBLK) void scan_local(const int* __restrict__ deg,
                                                   int* __restrict__ offsets,
                                                   int* __restrict__ bsum, int n1) {
    __shared__ int s[SBLK];
    int i = blockIdx.x * SBLK + threadIdx.x;
    int v = (i < n1 - 1) ? deg[i] : 0;
    s[threadIdx.x] = v;
    __syncthreads();
    for (int o = 1; o < SBLK; o <<= 1) {
        int add = (threadIdx.x >= o) ? s[threadIdx.x - o] : 0;
        __syncthreads();
        s[threadIdx.x] += add;
        __syncthreads();
    }
    if (i < n1) offsets[i] = s[threadIdx.x] - v;   // exclusive
    if (threadIdx.x == SBLK - 1) bsum[blockIdx.x] = s[SBLK - 1];
}

__global__ __launch_bounds__(SBLK) void scan_bsum(const int* __restrict__ bsum,
                                                  int* __restrict__ bbase, int nb) {
    __shared__ int s[SBLK];
    int v = (threadIdx.x < nb) ? bsum[threadIdx.x] : 0;
    s[threadIdx.x] = v;
    __syncthreads();
    for (int o = 1; o < 256; o <<= 1) {
        int add = (threadIdx.x >= o) ? s[threadIdx.x - o] : 0;
        __syncthreads();
        s[threadIdx.x] += add;
        __syncthreads();
    }
    if (threadIdx.x < nb) bbase[threadIdx.x] = s[threadIdx.x] - v;
}

__global__ __launch_bounds__(SBLK) void scan_add(int* __restrict__ offsets,
                                                 int* __restrict__ cursor,
                                                 const int* __restrict__ bbase, int n1) {
    int i = blockIdx.x * SBLK + threadIdx.x;
    if (i < n1) {
        int o = offsets[i] + bbase[blockIdx.x];
        offsets[i] = o;
        if (i < n1 - 1) cursor[i] = o;
    }
}

__global__ void fill_csr_perm(const int* __restrict__ src, const int* __restrict__ dst,
                              const float* __restrict__ w, const int* __restrict__ invp,
                              int* cur_d, int2* csrp, int E) {
    int e = blockIdx.x * blockDim.x + threadIdx.x;
    if (e < E) {
        int d = dst[e];
        int pd = atomicAdd(&cur_d[d], 1);
        csrp[pd] = make_int2(invp[src[e]], __float_as_int(w[e]));
    }
}

__global__ void build_rowrange(const int* __restrict__ offs, const int* __restrict__ perm,
                               int2* __restrict__ rowrange, int n) {
    int i = blockIdx.x * blockDim.x + threadIdx.x;
    if (i < n) {
        int j = perm[i];
        rowrange[i] = make_int2(offs[j], offs[j + 1]);
    }
}

// ---------------- degree-sorted permutation: contention-free block-local sort ----

__global__ __launch_bounds__(256) void bhist(const int* __restrict__ deg,
                                             int* __restrict__ bh, int n) {
    __shared__ int h[256];
    int t = threadIdx.x;
    h[t] = 0;
    __syncthreads();
    int i = blockIdx.x * 256 + t;
    if (i < n) {
        int d = deg[i]; if (d > 255) d = 255;
        atomicAdd(&h[d], 1);
    }
    __syncthreads();
    bh[t * NBK + blockIdx.x] = h[t];
}

__global__ __launch_bounds__(256) void bscatter(const int* __restrict__ deg,
                                                const int* __restrict__ obase,
                                                int* __restrict__ perm, int n) {
    __shared__ int cur[256];
    int t = threadIdx.x;
    cur[t] = obase[t * NBK + blockIdx.x];
    __syncthreads();
    int i = blockIdx.x * 256 + t;
    if (i < n) {
        int d = deg[i]; if (d > 255) d = 255;
        int p = atomicAdd(&cur[d], 1);
        perm[p] = i;
    }
}

__global__ void build_invperm(const int* __restrict__ perm, int* __restrict__ invp, int n) {
    int i = blockIdx.x * blockDim.x + threadIdx.x;
    if (i < n) invp[perm[i]] = i;
}

// ---------------- transpose X0 -> bf16, PERM-position row order ----------------

__global__ void transpose_x0_bf16(const float* __restrict__ X0, const int* __restrict__ invp,
                                  u16* Xb, int n) {
    __shared__ float tile[32][33];
    int jb = blockIdx.x * 32, tb = blockIdx.y * 32;
    int tx = threadIdx.x, ty = threadIdx.y;
    for (int r = 0; r < 32; r += 8) {
        int t = tb + ty + r, j = jb + tx;
        tile[ty + r][tx] = (j < n) ? X0[(size_t)t * n + j] : 0.f;
    }
    __syncthreads();
    for (int r = 0; r < 32; r += 8) {
        int j = jb + ty + r, t = tb + tx;
        if (j < n) Xb[(size_t)invp[j] * 128 + t] = f2bf(tile[tx][ty + r]);
    }
}

// ---------------- gemm_u via MFMA: Utb (perm-position rows) = F^T @ Om^T ----------------

__global__ __launch_bounds__(256) void gemm_u_mfma(const float* __restrict__ F,
                                                   const u16* __restrict__ Ofrg,
                                                   const int* __restrict__ invp,
                                                   u16* __restrict__ Utb, int n) {
    __shared__ u32 As32[64][17];
    int tid = threadIdx.x;
    int w = tid >> 6, l = tid & 63;
    int j0 = blockIdx.x * 64;
    const short8* __restrict__ bfr = (const short8*)Ofrg;
    f32x4 acc[8];
    #pragma unroll
    for (int nt = 0; nt < 8; ++nt) acc[nt] = (f32x4){0.f, 0.f, 0.f, 0.f};
    for (int kf = 0; kf < 8; ++kf) {
        int k0 = kf * 32;
        __syncthreads();
        #pragma unroll
        for (int r = 0; r < 4; ++r) {
            int idx = r * 256 + tid;
            int jj = idx & 63, kk2 = idx >> 6;
            int j = j0 + jj;
            float f0 = 0.f, f1 = 0.f;
            if (j < n) {
                f0 = F[(size_t)(k0 + 2 * kk2) * n + j];
                f1 = F[(size_t)(k0 + 2 * kk2 + 1) * n + j];
            }
            As32[jj][kk2] = pack2bf(f0, f1);
        }
        __syncthreads();
        u32 a0 = As32[w * 16 + (l & 15)][(l >> 4) * 4 + 0];
        u32 a1 = As32[w * 16 + (l & 15)][(l >> 4) * 4 + 1];
        u32 a2 = As32[w * 16 + (l & 15)][(l >> 4) * 4 + 2];
        u32 a3 = As32[w * 16 + (l & 15)][(l >> 4) * 4 + 3];
        short8 a;
        a[0] = (short)(a0 & 0xffff); a[1] = (short)(a0 >> 16);
        a[2] = (short)(a1 & 0xffff); a[3] = (short)(a1 >> 16);
        a[4] = (short)(a2 & 0xffff); a[5] = (short)(a2 >> 16);
        a[6] = (short)(a3 & 0xffff); a[7] = (short)(a3 >> 16);
        #pragma unroll
        for (int nt = 0; nt < 8; ++nt) {
            short8 b = bfr[(kf * 8 + nt) * 64 + l];
            acc[nt] = __builtin_amdgcn_mfma_f32_16x16x32_bf16(a, b, acc[nt], 0, 0, 0);
        }
    }
    int rbase = j0 + w * 16 + (l >> 4) * 4;
    int cbase = l & 15;
    int prow[4];
    #pragma unroll
    for (int i = 0; i < 4; ++i) {
        int row = rbase + i;
        prow[i] = (row < n) ? invp[row] : -1;
    }
    #pragma unroll
    for (int nt = 0; nt < 8; ++nt) {
        int col = nt * 16 + cbase;
        #pragma unroll
        for (int i = 0; i < 4; ++i) {
            if (prow[i] >= 0) Utb[(size_t)prow[i] * 128 + col] = f2bf(acc[nt][i]);
        }
    }
}

// ---------------- reorder bias into MFMA C-fragment layout (all perm-space) ----------

__global__ __launch_bounds__(256) void reorder_bt(const u16* __restrict__ btr,
                                                  uint2* __restrict__ btf, int n) {
    int t = blockIdx.y * 256 + threadIdx.x;   // 0..511
    int idx16 = blockIdx.x;
    int nt = t >> 6, lane = t & 63;
    int r0 = idx16 * 16 + (lane >> 4) * 4;
    int c = nt * 16 + (lane & 15);
    u16 b0 = (r0 + 0 < n) ? btr[(size_t)(r0 + 0) * 128 + c] : 0;
    u16 b1 = (r0 + 1 < n) ? btr[(size_t)(r0 + 1) * 128 + c] : 0;
    u16 b2 = (r0 + 2 < n) ? btr[(size_t)(r0 + 2) * 128 + c] : 0;
    u16 b3 = (r0 + 3 < n) ? btr[(size_t)(r0 + 3) * 128 + c] : 0;
    uint2 o;
    o.x = (u32)b0 | ((u32)b1 << 16);
    o.y = (u32)b2 | ((u32)b3 << 16);
    btf[(size_t)(idx16 * 8 + nt) * 64 + lane] = o;
}

// ---------------- spmm bf16 (bias path), all perm-space ----------------

__global__ __launch_bounds__(256) void spmm_bf16(const int2* __restrict__ rowrange,
                                                 const int2* __restrict__ csrp,
                                                 const u16* __restrict__ Xin,
                                                 u16* __restrict__ Yout, int n) {
    int tid = threadIdx.x;
    int wid = tid >> 6, lane = tid & 63;
    int q = lane >> 4, li = lane & 15;
    int jp = blockIdx.x * 16 + wid * 4 + q;
    if (jp >= n) return;
    int2 rr = rowrange[jp];
    const uint4* __restrict__ X4 = (const uint4*)Xin;
    float a[8] = {};
    int e = rr.x;
    for (; e + 8 <= rr.y; e += 8) {
        int2 c[8];
        #pragma unroll
        for (int u = 0; u < 8; ++u) c[u] = csrp[e + u];
        uint4 x[8];
        #pragma unroll
        for (int u = 0; u < 8; ++u) x[u] = X4[(size_t)c[u].x * 16 + li];
        #pragma unroll
        for (int u = 0; u < 8; ++u) {
            float w = __int_as_float(c[u].y);
            a[0] += w * bflo(x[u].x); a[1] += w * bfhi(x[u].x);
            a[2] += w * bflo(x[u].y); a[3] += w * bfhi(x[u].y);
            a[4] += w * bflo(x[u].z); a[5] += w * bfhi(x[u].z);
            a[6] += w * bflo(x[u].w); a[7] += w * bfhi(x[u].w);
        }
    }
    for (; e < rr.y; ++e) {
        int2 c = csrp[e];
        float w = __int_as_float(c.y);
        uint4 x = X4[(size_t)c.x * 16 + li];
        a[0] += w * bflo(x.x); a[1] += w * bfhi(x.x);
        a[2] += w * bflo(x.y); a[3] += w * bfhi(x.y);
        a[4] += w * bflo(x.z); a[5] += w * bfhi(x.z);
        a[6] += w * bflo(x.w); a[7] += w * bfhi(x.w);
    }
    uint4 o;
    o.x = pack2bf(a[0], a[1]);
    o.y = pack2bf(a[2], a[3]);
    o.z = pack2bf(a[4], a[5]);
    o.w = pack2bf(a[6], a[7]);
    ((uint4*)Yout)[(size_t)jp * 16 + li] = o;
}

// ---------------- fused FP step, all perm-space ----------------

__global__ __launch_bounds__(512) void fused_fp(const int2* __restrict__ rowrange,
                                                const int2* __restrict__ csrp,
                                                const u16* __restrict__ Xin,
                                                const u16* __restrict__ Bswz,
                                                const uint2* __restrict__ btf,
                                                u16* __restrict__ Xout, int n) {
    __shared__ uint4 Ys[32][17];
    int tid = threadIdx.x;

    // ---- gather phase: quarter-wave per permuted row ----
    {
        int qw = tid >> 4, li = tid & 15;
        int jp = blockIdx.x * 32 + qw;
        float a[8] = {};
        if (jp < n) {
            int2 rr = rowrange[jp];
            const uint4* __restrict__ X4 = (const uint4*)Xin;
            int e = rr.x;
            for (; e + 8 <= rr.y; e += 8) {
                int2 c[8];
                #pragma unroll
                for (int u = 0; u < 8; ++u) c[u] = csrp[e + u];
                uint4 x[8];
                #pragma unroll
                for (int u = 0; u < 8; ++u) x[u] = X4[(size_t)c[u].x * 16 + li];
                #pragma unroll
                for (int u = 0; u < 8; ++u) {
                    float w = __int_as_float(c[u].y);
                    a[0] += w * bflo(x[u].x); a[1] += w * bfhi(x[u].x);
                    a[2] += w * bflo(x[u].y); a[3] += w * bfhi(x[u].y);
                    a[4] += w * bflo(x[u].z); a[5] += w * bfhi(x[u].z);
                    a[6] += w * bflo(x[u].w); a[7] += w * bfhi(x[u].w);
                }
            }
            for (; e < rr.y; ++e) {
                int2 c = csrp[e];
                float w = __int_as_float(c.y);
                uint4 x = X4[(size_t)c.x * 16 + li];
                a[0] += w * bflo(x.x); a[1] += w * bfhi(x.x);
                a[2] += w * bflo(x.y); a[3] += w * bfhi(x.y);
                a[4] += w * bflo(x.z); a[5] += w * bfhi(x.z);
                a[6] += w * bflo(x.w); a[7] += w * bfhi(x.w);
            }
        }
        uint4 o;
        o.x = pack2bf(a[0], a[1]);
        o.y = pack2bf(a[2], a[3]);
        o.z = pack2bf(a[4], a[5]);
        o.w = pack2bf(a[6], a[7]);
        Ys[qw][li] = o;
    }
    __syncthreads();

    // ---- MFMA phase ----
    int w = tid >> 6, l = tid & 63;
    int rg = w & 1;
    int ntb = (w >> 1) * 2;
    f32x4 acc[2];
    acc[0] = (f32x4){0.f, 0.f, 0.f, 0.f};
    acc[1] = (f32x4){0.f, 0.f, 0.f, 0.f};
    const short8* __restrict__ bfr = (const short8*)Bswz;
    #pragma unroll
    for (int kf = 0; kf < 4; ++kf) {
        short8 a = *((const short8*)&Ys[rg * 16 + (l & 15)][kf * 4 + (l >> 4)]);
        #pragma unroll
        for (int t = 0; t < 2; ++t) {
            short8 b = bfr[(kf * 8 + ntb + t) * 64 + l];
            acc[t] = __builtin_amdgcn_mfma_f32_16x16x32_bf16(a, b, acc[t], 0, 0, 0);
        }
    }
    int pidx16 = blockIdx.x * 2 + rg;
    int lrbase = rg * 16 + (l >> 4) * 4;
    int cbase = l & 15;
    #pragma unroll
    for (int t = 0; t < 2; ++t) {
        int nt = ntb + t;
        uint2 bb = btf[(size_t)(pidx16 * 8 + nt) * 64 + l];
        float bi[4] = {bflo(bb.x), bfhi(bb.x), bflo(bb.y), bfhi(bb.y)};
        int col = nt * 16 + cbase;
        #pragma unroll
        for (int i = 0; i < 4; ++i) {
            int jp = blockIdx.x * 32 + lrbase + i;
            if (jp < n) {
                float v = acc[t][i] + bi[i];
                Xout[(size_t)jp * 128 + col] = f2bf(v > 0.f ? v : 0.f);
            }
        }
    }
}

// ---------------- final: normalize rows + H @ Vw^T (perm-space input) ----------------

__global__ __launch_bounds__(256) void final_out(const u16* __restrict__ Xb,
                                                 const int* __restrict__ perm,
                                                 const float* __restrict__ Vw,
                                                 float* __restrict__ out, int n) {
    __shared__ float Vs[40][132];
    int tid = threadIdx.x;
    int jb = blockIdx.x * 64;
    for (int i = tid; i < 40 * 128; i += 256) {
        int c = i >> 7, k = i & 127;
        Vs[c][(k >> 5) * 33 + (k & 31)] = Vw[i];
    }
    int g = tid >> 2, q = tid & 3;
    int jp = jb + g;
    float xs[32];
    float ssq = 0.f;
    if (jp < n) {
        const uint4* X4 = (const uint4*)(Xb + (size_t)jp * 128) + q * 4;
        #pragma unroll
        for (int v = 0; v < 4; ++v) {
            uint4 u = X4[v];
            xs[v * 8 + 0] = bflo(u.x); xs[v * 8 + 1] = bfhi(u.x);
            xs[v * 8 + 2] = bflo(u.y); xs[v * 8 + 3] = bfhi(u.y);
            xs[v * 8 + 4] = bflo(u.z); xs[v * 8 + 5] = bfhi(u.z);
            xs[v * 8 + 6] = bflo(u.w); xs[v * 8 + 7] = bfhi(u.w);
        }
        #pragma unroll
        for (int m = 0; m < 32; ++m) ssq += xs[m] * xs[m];
    } else {
        #pragma unroll
        for (int m = 0; m < 32; ++m) xs[m] = 0.f;
    }
    ssq += __shfl_xor(ssq, 1, 64);
    ssq += __shfl_xor(ssq, 2, 64);
    float inv = 1.f / fmaxf(sqrtf(ssq), 1e-12f);
    #pragma unroll
    for (int m = 0; m < 32; ++m) xs[m] *= inv;
    __syncthreads();
    float pacc[10];
    #pragma unroll
    for (int cc = 0; cc < 10; ++cc) pacc[cc] = 0.f;
    #pragma unroll 1
    for (int c = 0; c < 40; ++c) {
        const float* vrow = &Vs[c][q * 33];
        float acc = 0.f;
        #pragma unroll
        for (int m = 0; m < 32; ++m) acc += xs[m] * vrow[m];
        acc += __shfl_xor(acc, 1, 64);
        acc += __shfl_xor(acc, 2, 64);
        if ((c & 3) == q) pacc[c >> 2] = acc;
    }
    if (jp < n) {
        int j = perm[jp];
        #pragma unroll
        for (int cc = 0; cc < 10; ++cc) {
            int c = cc * 4 + q;
            out[(size_t)j * 40 + c] = pacc[cc];
        }
    }
}

// ---------------- launch ----------------

extern "C" void kernel_launch(void* const* d_in, const int* in_sizes, int n_in,
                              void* d_out, int out_size, void* d_ws, size_t ws_size,
                              hipStream_t stream) {
    const float* F    = (const float*)d_in[0];   // (256, 50000)
    const float* W    = (const float*)d_in[1];   // (128, 128)
    const float* Om   = (const float*)d_in[2];   // (128, 256)
    const float* Vw   = (const float*)d_in[3];   // (40, 128)
    const float* X0   = (const float*)d_in[4];   // (128, 50000)
    const float* ew   = (const float*)d_in[5];   // (E,)
    const int*   esrc = (const int*)d_in[6];
    const int*   edst = (const int*)d_in[7];
    float* out = (float*)d_out;
    (void)in_sizes; (void)n_in; (void)out_size; (void)ws_size;

    char* ws = (char*)d_ws;
    size_t off = 0;
    auto alloc = [&](size_t bytes) -> void* {
        void* p = ws + off;
        off = (off + bytes + 255) & ~(size_t)255;
        return p;
    };
    float* buf0    = (float*)alloc((size_t)N_NODES * 4);
    float* buf1    = (float*)alloc((size_t)N_NODES * 4);
    float* ss      = (float*)alloc(64 * 4);
    int*   deg     = (int*)  alloc((size_t)(N_NODES + 1) * 4);
    int*   offs_d  = (int*)  alloc((size_t)(N_NODES + 1) * 4);
    int*   cur_d   = (int*)  alloc((size_t)N_NODES * 4);
    int*   bsum    = (int*)  alloc(512 * 4);
    int*   bbase   = (int*)  alloc(512 * 4);
    int*   bh      = (int*)  alloc((size_t)(256 * NBK + 1) * 4);
    int*   obase   = (int*)  alloc((size_t)(256 * NBK + 1) * 4);
    int*   ocur    = (int*)  alloc((size_t)(256 * NBK + 1) * 4);
    int*   perm    = (int*)  alloc((size_t)N_NODES * 4);
    int*   invp    = (int*)  alloc((size_t)N_NODES * 4);
    int2*  rowrng  = (int2*) alloc((size_t)N_NODES * 8);
    int2*  csrp    = (int2*) alloc((size_t)N_EDGES * 8);   // by-dst, src in perm space
    u16*   Bswz    = (u16*)  alloc(128 * 128 * 2);
    u16*   Ofrg    = (u16*)  alloc(128 * 256 * 2);
    u16*   btr     = (u16*)  alloc((size_t)N_NODES * 128 * 2);    // bias (perm-space rows)
    uint2* btf     = (uint2*)alloc((size_t)3200 * 512 * 8);       // bias C-frag
    u16*   Utb     = (u16*)  alloc((size_t)N_NODES * 128 * 2);    // perm-space rows
    u16*   Xa      = (u16*)  alloc((size_t)N_NODES * 128 * 2);
    u16*   Xb      = (u16*)  alloc((size_t)N_NODES * 128 * 2);

    hipMemsetAsync(deg, 0, (size_t)(N_NODES + 1) * 4, stream);

    const int n1 = N_NODES + 1;
    const int nb = (n1 + SBLK - 1) / SBLK;   // 196 <= 256

    // ---- degree count + offsets ----
    count_deg<<<(N_EDGES + 255) / 256, 256, 0, stream>>>(edst, deg, N_EDGES);
    scan_local<<<nb, SBLK, 0, stream>>>(deg, offs_d, bsum, n1);
    scan_bsum<<<1, SBLK, 0, stream>>>(bsum, bbase, nb);
    scan_add<<<nb, SBLK, 0, stream>>>(offs_d, cur_d, bbase, n1);

    // ---- degree-sorted permutation (contention-free block-local counting sort) ----
    bhist<<<NBK, 256, 0, stream>>>(deg, bh, N_NODES);
    {
        const int sn1 = 256 * NBK + 1;
        const int snb = (sn1 + SBLK - 1) / SBLK;   // 197 <= 256
        scan_local<<<snb, SBLK, 0, stream>>>(bh, obase, bsum, sn1);
        scan_bsum<<<1, SBLK, 0, stream>>>(bsum, bbase, snb);
        scan_add<<<snb, SBLK, 0, stream>>>(obase, ocur, bbase, sn1);
    }
    bscatter<<<NBK, 256, 0, stream>>>(deg, obase, perm, N_NODES);
    build_invperm<<<(N_NODES + 255) / 256, 256, 0, stream>>>(perm, invp, N_NODES);

    // ---- CSR fill directly in perm space + row ranges ----
    fill_csr_perm<<<(N_EDGES + 255) / 256, 256, 0, stream>>>(
        esrc, edst, ew, invp, cur_d, csrp, N_EDGES);
    build_rowrange<<<(N_NODES + 255) / 256, 256, 0, stream>>>(offs_d, perm, rowrng, N_NODES);

    // ---- power iteration on A^T (discrete launches; coop grid.sync is 20x slower) ----
    fill_pow<<<(N_NODES + 255) / 256, 256, 0, stream>>>(
        buf0, ss, N_NODES, 1.f / sqrtf((float)N_NODES));
    float* bufs[2] = {buf0, buf1};
    for (int it = 0; it <= PWR_ITERS; ++it) {
        matvec_norm<<<(8 * N_NODES + 255) / 256, 256, 0, stream>>>(
            rowrng, csrp, bufs[it & 1], ss + it,
            bufs[(it + 1) & 1], ss + it + 1, N_NODES);
    }

    // ---- project W (rho^2 = ss[PWR_ITERS+1]) -> Bswz fragments ----
    project_w<<<128, 128, 0, stream>>>(W, ss + PWR_ITERS + 1, Bswz);

    // ---- b = (Omega_1 @ U) @ A : all perm-space ----
    reorder_om<<<128, 256, 0, stream>>>(Om, Ofrg);
    gemm_u_mfma<<<(N_NODES + 63) / 64, 256, 0, stream>>>(F, Ofrg, invp, Utb, N_NODES);
    spmm_bf16<<<(N_NODES + 15) / 16, 256, 0, stream>>>(rowrng, csrp, Utb, btr, N_NODES);
    reorder_bt<<<dim3((N_NODES + 15) / 16, 2), 256, 0, stream>>>(btr, btf, N_NODES);

    // ---- fixed point (fused, perm-space X) ----
    transpose_x0_bf16<<<dim3((N_NODES + 31) / 32, 4), dim3(32, 8), 0, stream>>>(X0, invp, Xa, N_NODES);
    u16* xb2[2] = {Xa, Xb};
    for (int it = 0; it < FP_ITERS; ++it) {
        fused_fp<<<(N_NODES + 31) / 32, 512, 0, stream>>>(
            rowrng, csrp, xb2[it & 1], Bswz, btf, xb2[(it + 1) & 1], N_NODES);
    }

    // ---- output ----
    final_out<<<(N_NODES + 63) / 64, 256, 0, stream>>>(xb2[FP_ITERS & 1], perm, Vw, out, N_NODES);
}

// Round 17
// 1764.079 us; speedup vs baseline: 2.6155x; 1.0128x over previous
//
#include <hip/hip_runtime.h>
#include <math.h>

#define N_NODES 50000
#define N_EDGES 800000
#define M_HID   128
#define P_FEAT  256
#define C_OUT   40
#define PWR_ITERS 8
#define FP_ITERS  30
#define KAPPA 0.9f
#define SBLK 256
#define NBK ((N_NODES + 255) / 256)   // 196 histogram blocks

typedef unsigned short u16;
typedef unsigned int   u32;
typedef __attribute__((ext_vector_type(8))) short short8;
typedef __attribute__((ext_vector_type(4))) float f32x4;

// bf16 helpers (RNE)
__device__ inline u16 f2bf(float f) {
    union { float f; u32 u; } c; c.f = f;
    u32 u = c.u + 0x7fffu + ((c.u >> 16) & 1u);
    return (u16)(u >> 16);
}
__device__ inline u32 pack2bf(float lo, float hi) {
    return (u32)f2bf(lo) | ((u32)f2bf(hi) << 16);
}
__device__ inline float bflo(u32 u) { union { u32 u; float f; } c; c.u = u << 16; return c.f; }
__device__ inline float bfhi(u32 u) { union { u32 u; float f; } c; c.u = u & 0xffff0000u; return c.f; }

// ---------------- init ----------------

__global__ void fill_pow(float* buf0, float* ss, int n, float val) {
    int i = blockIdx.x * blockDim.x + threadIdx.x;
    if (i < n) buf0[i] = val;
    if (blockIdx.x == 0 && threadIdx.x < 64) ss[threadIdx.x] = (threadIdx.x == 0) ? 1.f : 0.f;
}

// ---------------- power iteration on A^T, fully perm-space ----------------

__global__ __launch_bounds__(256) void matvec_norm(const int2* __restrict__ rowrange,
                                                   const int2* __restrict__ csrp,
                                                   const float* __restrict__ vin,
                                                   const float* __restrict__ n2in,
                                                   float* __restrict__ vout,
                                                   float* n2out, int n) {
    int t = blockIdx.x * blockDim.x + threadIdx.x;
    int g = t >> 3, q = t & 7;
    float inv = 1.f / (sqrtf(*n2in) + 1e-12f);
    float a = 0.f;
    if (g < n) {
        int2 rr = rowrange[g];
        for (int e = rr.x + q; e < rr.y; e += 8) {
            int2 c = csrp[e];
            a += __int_as_float(c.y) * vin[c.x];
        }
    }
    a += __shfl_xor(a, 1, 64);
    a += __shfl_xor(a, 2, 64);
    a += __shfl_xor(a, 4, 64);
    a *= inv;
    if (g < n && q == 0) vout[g] = a;
    float s = (q == 0 && g < n) ? a * a : 0.f;
    for (int o = 32; o > 0; o >>= 1) s += __shfl_down(s, o, 64);
    __shared__ float ls[4];
    int lane = threadIdx.x & 63, wid = threadIdx.x >> 6;
    if (lane == 0) ls[wid] = s;
    __syncthreads();
    if (threadIdx.x == 0) atomicAdd(n2out, ls[0] + ls[1] + ls[2] + ls[3]);
}

// ---------------- L1-ball row projection of W -> MFMA B-fragment layout ----------------

__global__ __launch_bounds__(128) void project_w(const float* __restrict__ W,
                                                 const float* __restrict__ rho2,
                                                 u16* __restrict__ Bswz) {
    __shared__ float sa[128];
    __shared__ float ssort[128];
    __shared__ float sc[128];
    __shared__ int cnt2[2];
    int r = blockIdx.x, t = threadIdx.x;
    float radius = KAPPA / sqrtf(*rho2);
    float w0 = W[r * 128 + t];
    float a = fabsf(w0);
    sa[t] = a;
    __syncthreads();
    int rank = 0;
    #pragma unroll 8
    for (int j = 0; j < 128; ++j) {
        float aj = sa[j];
        rank += (aj > a) || (aj == a && j < t);
    }
    ssort[rank] = a;
    __syncthreads();
    sc[t] = ssort[t];
    __syncthreads();
    for (int off = 1; off < 128; off <<= 1) {
        float add = (t >= off) ? sc[t - off] : 0.f;
        __syncthreads();
        sc[t] += add;
        __syncthreads();
    }
    bool flag = ssort[t] * (float)(t + 1) > sc[t] - radius;
    unsigned long long b = __ballot(flag);
    if ((t & 63) == 0) cnt2[t >> 6] = __popcll(b);
    __syncthreads();
    int rho = cnt2[0] + cnt2[1];
    float total = sc[127];
    bool needs = total > radius;
    float theta = (sc[rho - 1] - radius) / (float)rho;
    float o;
    if (needs) {
        float am = a - theta;
        o = (am > 0.f) ? ((w0 > 0.f) ? am : -am) : 0.f;
    } else o = w0;
    int kf = t >> 5, quad = (t >> 3) & 3, jj = t & 7;
    int nt = r >> 4, li = r & 15;
    int l = quad * 16 + li;
    Bswz[((size_t)(kf * 8 + nt) * 64 + l) * 8 + jj] = f2bf(o);
}

// ---------------- Omega_1 -> MFMA B-fragment layout (K=256: kf 0..7) ----------------

__global__ __launch_bounds__(256) void reorder_om(const float* __restrict__ Om,
                                                  u16* __restrict__ Ofrg) {
    int idx = blockIdx.x * 256 + threadIdx.x;   // 128*256
    int r = idx >> 8, k = idx & 255;
    int nt = r >> 4, li = r & 15;
    int kf = k >> 5, sub = (k >> 3) & 3, jj = k & 7;
    int l = sub * 16 + li;
    Ofrg[((size_t)(kf * 8 + nt) * 64 + l) * 8 + jj] = f2bf(Om[idx]);
}

// ---------------- CSR build, PERM-SPACE src indices ----------------

__global__ void count_deg(const int* __restrict__ dst, int* deg, int E) {
    int e = blockIdx.x * blockDim.x + threadIdx.x;
    if (e < E) atomicAdd(&deg[dst[e]], 1);
}

__global__ __launch_bounds__(SBLK) void scan_local(const int* __restrict__ deg,
                                                   int* __restrict__ offsets,
                                                   int* __restrict__ bsum, int n1) {
    __shared__ int s[SBLK];
    int i = blockIdx.x * SBLK + threadIdx.x;
    int v = (i < n1 - 1) ? deg[i] : 0;
    s[threadIdx.x] = v;
    __syncthreads();
    for (int o = 1; o < SBLK; o <<= 1) {
        int add = (threadIdx.x >= o) ? s[threadIdx.x - o] : 0;
        __syncthreads();
        s[threadIdx.x] += add;
        __syncthreads();
    }
    if (i < n1) offsets[i] = s[threadIdx.x] - v;   // exclusive
    if (threadIdx.x == SBLK - 1) bsum[blockIdx.x] = s[SBLK - 1];
}

__global__ __launch_bounds__(SBLK) void scan_bsum(const int* __restrict__ bsum,
                                                  int* __restrict__ bbase, int nb) {
    __shared__ int s[SBLK];
    int v = (threadIdx.x < nb) ? bsum[threadIdx.x] : 0;
    s[threadIdx.x] = v;
    __syncthreads();
    for (int o = 1; o < 256; o <<= 1) {
        int add = (threadIdx.x >= o) ? s[threadIdx.x - o] : 0;
        __syncthreads();
        s[threadIdx.x] += add;
        __syncthreads();
    }
    if (threadIdx.x < nb) bbase[threadIdx.x] = s[threadIdx.x] - v;
}

__global__ __launch_bounds__(SBLK) void scan_add(int* __restrict__ offsets,
                                                 int* __restrict__ cursor,
                                                 const int* __restrict__ bbase, int n1) {
    int i = blockIdx.x * SBLK + threadIdx.x;
    if (i < n1) {
        int o = offsets[i] + bbase[blockIdx.x];
        offsets[i] = o;
        if (i < n1 - 1) cursor[i] = o;
    }
}

__global__ void fill_csr_perm(const int* __restrict__ src, const int* __restrict__ dst,
                              const float* __restrict__ w, const int* __restrict__ invp,
                              int* cur_d, int2* csrp, int E) {
    int e = blockIdx.x * blockDim.x + threadIdx.x;
    if (e < E) {
        int d = dst[e];
        int pd = atomicAdd(&cur_d[d], 1);
        csrp[pd] = make_int2(invp[src[e]], __float_as_int(w[e]));
    }
}

__global__ void build_rowrange(const int* __restrict__ offs, const int* __restrict__ perm,
                               int2* __restrict__ rowrange, int n) {
    int i = blockIdx.x * blockDim.x + threadIdx.x;
    if (i < n) {
        int j = perm[i];
        rowrange[i] = make_int2(offs[j], offs[j + 1]);
    }
}

// ---------------- degree-sorted permutation: contention-free block-local sort ----

__global__ __launch_bounds__(256) void bhist(const int* __restrict__ deg,
                                             int* __restrict__ bh, int n) {
    __shared__ int h[256];
    int t = threadIdx.x;
    h[t] = 0;
    __syncthreads();
    int i = blockIdx.x * 256 + t;
    if (i < n) {
        int d = deg[i]; if (d > 255) d = 255;
        atomicAdd(&h[d], 1);
    }
    __syncthreads();
    bh[t * NBK + blockIdx.x] = h[t];
}

__global__ __launch_bounds__(256) void bscatter(const int* __restrict__ deg,
                                                const int* __restrict__ obase,
                                                int* __restrict__ perm, int n) {
    __shared__ int cur[256];
    int t = threadIdx.x;
    cur[t] = obase[t * NBK + blockIdx.x];
    __syncthreads();
    int i = blockIdx.x * 256 + t;
    if (i < n) {
        int d = deg[i]; if (d > 255) d = 255;
        int p = atomicAdd(&cur[d], 1);
        perm[p] = i;
    }
}

__global__ void build_invperm(const int* __restrict__ perm, int* __restrict__ invp, int n) {
    int i = blockIdx.x * blockDim.x + threadIdx.x;
    if (i < n) invp[perm[i]] = i;
}

// ---------------- transpose X0 -> bf16, PERM-position row order ----------------

__global__ void transpose_x0_bf16(const float* __restrict__ X0, const int* __restrict__ invp,
                                  u16* Xb, int n) {
    __shared__ float tile[32][33];
    int jb = blockIdx.x * 32, tb = blockIdx.y * 32;
    int tx = threadIdx.x, ty = threadIdx.y;
    for (int r = 0; r < 32; r += 8) {
        int t = tb + ty + r, j = jb + tx;
        tile[ty + r][tx] = (j < n) ? X0[(size_t)t * n + j] : 0.f;
    }
    __syncthreads();
    for (int r = 0; r < 32; r += 8) {
        int j = jb + ty + r, t = tb + tx;
        if (j < n) Xb[(size_t)invp[j] * 128 + t] = f2bf(tile[tx][ty + r]);
    }
}

// ---------------- gemm_u via MFMA: Utb (perm-position rows) = F^T @ Om^T ----------------

__global__ __launch_bounds__(256) void gemm_u_mfma(const float* __restrict__ F,
                                                   const u16* __restrict__ Ofrg,
                                                   const int* __restrict__ invp,
                                                   u16* __restrict__ Utb, int n) {
    __shared__ u32 As32[64][17];
    int tid = threadIdx.x;
    int w = tid >> 6, l = tid & 63;
    int j0 = blockIdx.x * 64;
    const short8* __restrict__ bfr = (const short8*)Ofrg;
    f32x4 acc[8];
    #pragma unroll
    for (int nt = 0; nt < 8; ++nt) acc[nt] = (f32x4){0.f, 0.f, 0.f, 0.f};
    for (int kf = 0; kf < 8; ++kf) {
        int k0 = kf * 32;
        __syncthreads();
        #pragma unroll
        for (int r = 0; r < 4; ++r) {
            int idx = r * 256 + tid;
            int jj = idx & 63, kk2 = idx >> 6;
            int j = j0 + jj;
            float f0 = 0.f, f1 = 0.f;
            if (j < n) {
                f0 = F[(size_t)(k0 + 2 * kk2) * n + j];
                f1 = F[(size_t)(k0 + 2 * kk2 + 1) * n + j];
            }
            As32[jj][kk2] = pack2bf(f0, f1);
        }
        __syncthreads();
        u32 a0 = As32[w * 16 + (l & 15)][(l >> 4) * 4 + 0];
        u32 a1 = As32[w * 16 + (l & 15)][(l >> 4) * 4 + 1];
        u32 a2 = As32[w * 16 + (l & 15)][(l >> 4) * 4 + 2];
        u32 a3 = As32[w * 16 + (l & 15)][(l >> 4) * 4 + 3];
        short8 a;
        a[0] = (short)(a0 & 0xffff); a[1] = (short)(a0 >> 16);
        a[2] = (short)(a1 & 0xffff); a[3] = (short)(a1 >> 16);
        a[4] = (short)(a2 & 0xffff); a[5] = (short)(a2 >> 16);
        a[6] = (short)(a3 & 0xffff); a[7] = (short)(a3 >> 16);
        #pragma unroll
        for (int nt = 0; nt < 8; ++nt) {
            short8 b = bfr[(kf * 8 + nt) * 64 + l];
            acc[nt] = __builtin_amdgcn_mfma_f32_16x16x32_bf16(a, b, acc[nt], 0, 0, 0);
        }
    }
    int rbase = j0 + w * 16 + (l >> 4) * 4;
    int cbase = l & 15;
    int prow[4];
    #pragma unroll
    for (int i = 0; i < 4; ++i) {
        int row = rbase + i;
        prow[i] = (row < n) ? invp[row] : -1;
    }
    #pragma unroll
    for (int nt = 0; nt < 8; ++nt) {
        int col = nt * 16 + cbase;
        #pragma unroll
        for (int i = 0; i < 4; ++i) {
            if (prow[i] >= 0) Utb[(size_t)prow[i] * 128 + col] = f2bf(acc[nt][i]);
        }
    }
}

// ---------------- reorder bias into MFMA C-fragment layout (all perm-space) ----------

__global__ __launch_bounds__(256) void reorder_bt(const u16* __restrict__ btr,
                                                  uint2* __restrict__ btf, int n) {
    int t = blockIdx.y * 256 + threadIdx.x;   // 0..511
    int idx16 = blockIdx.x;
    int nt = t >> 6, lane = t & 63;
    int r0 = idx16 * 16 + (lane >> 4) * 4;
    int c = nt * 16 + (lane & 15);
    u16 b0 = (r0 + 0 < n) ? btr[(size_t)(r0 + 0) * 128 + c] : 0;
    u16 b1 = (r0 + 1 < n) ? btr[(size_t)(r0 + 1) * 128 + c] : 0;
    u16 b2 = (r0 + 2 < n) ? btr[(size_t)(r0 + 2) * 128 + c] : 0;
    u16 b3 = (r0 + 3 < n) ? btr[(size_t)(r0 + 3) * 128 + c] : 0;
    uint2 o;
    o.x = (u32)b0 | ((u32)b1 << 16);
    o.y = (u32)b2 | ((u32)b3 << 16);
    btf[(size_t)(idx16 * 8 + nt) * 64 + lane] = o;
}

// ---------------- spmm bf16 (bias path), all perm-space, 16-deep gather ----------------

__global__ __launch_bounds__(256) void spmm_bf16(const int2* __restrict__ rowrange,
                                                 const int2* __restrict__ csrp,
                                                 const u16* __restrict__ Xin,
                                                 u16* __restrict__ Yout, int n) {
    int tid = threadIdx.x;
    int wid = tid >> 6, lane = tid & 63;
    int q = lane >> 4, li = lane & 15;
    int jp = blockIdx.x * 16 + wid * 4 + q;
    if (jp >= n) return;
    int2 rr = rowrange[jp];
    const uint4* __restrict__ X4 = (const uint4*)Xin;
    float a[8] = {};
    int e = rr.x;
    for (; e + 16 <= rr.y; e += 16) {
        int2 c[16];
        #pragma unroll
        for (int u = 0; u < 16; ++u) c[u] = csrp[e + u];
        uint4 x[16];
        #pragma unroll
        for (int u = 0; u < 16; ++u) x[u] = X4[(size_t)c[u].x * 16 + li];
        #pragma unroll
        for (int u = 0; u < 16; ++u) {
            float w = __int_as_float(c[u].y);
            a[0] += w * bflo(x[u].x); a[1] += w * bfhi(x[u].x);
            a[2] += w * bflo(x[u].y); a[3] += w * bfhi(x[u].y);
            a[4] += w * bflo(x[u].z); a[5] += w * bfhi(x[u].z);
            a[6] += w * bflo(x[u].w); a[7] += w * bfhi(x[u].w);
        }
    }
    for (; e + 8 <= rr.y; e += 8) {
        int2 c[8];
        #pragma unroll
        for (int u = 0; u < 8; ++u) c[u] = csrp[e + u];
        uint4 x[8];
        #pragma unroll
        for (int u = 0; u < 8; ++u) x[u] = X4[(size_t)c[u].x * 16 + li];
        #pragma unroll
        for (int u = 0; u < 8; ++u) {
            float w = __int_as_float(c[u].y);
            a[0] += w * bflo(x[u].x); a[1] += w * bfhi(x[u].x);
            a[2] += w * bflo(x[u].y); a[3] += w * bfhi(x[u].y);
            a[4] += w * bflo(x[u].z); a[5] += w * bfhi(x[u].z);
            a[6] += w * bflo(x[u].w); a[7] += w * bfhi(x[u].w);
        }
    }
    for (; e < rr.y; ++e) {
        int2 c = csrp[e];
        float w = __int_as_float(c.y);
        uint4 x = X4[(size_t)c.x * 16 + li];
        a[0] += w * bflo(x.x); a[1] += w * bfhi(x.x);
        a[2] += w * bflo(x.y); a[3] += w * bfhi(x.y);
        a[4] += w * bflo(x.z); a[5] += w * bfhi(x.z);
        a[6] += w * bflo(x.w); a[7] += w * bfhi(x.w);
    }
    uint4 o;
    o.x = pack2bf(a[0], a[1]);
    o.y = pack2bf(a[2], a[3]);
    o.z = pack2bf(a[4], a[5]);
    o.w = pack2bf(a[6], a[7]);
    ((uint4*)Yout)[(size_t)jp * 16 + li] = o;
}

// ---------------- fused FP step, all perm-space, 16-deep gather ----------------

__global__ __launch_bounds__(512) void fused_fp(const int2* __restrict__ rowrange,
                                                const int2* __restrict__ csrp,
                                                const u16* __restrict__ Xin,
                                                const u16* __restrict__ Bswz,
                                                const uint2* __restrict__ btf,
                                                u16* __restrict__ Xout, int n) {
    __shared__ uint4 Ys[32][17];
    int tid = threadIdx.x;

    // ---- gather phase: quarter-wave per permuted row ----
    {
        int qw = tid >> 4, li = tid & 15;
        int jp = blockIdx.x * 32 + qw;
        float a[8] = {};
        if (jp < n) {
            int2 rr = rowrange[jp];
            const uint4* __restrict__ X4 = (const uint4*)Xin;
            int e = rr.x;
            for (; e + 16 <= rr.y; e += 16) {
                int2 c[16];
                #pragma unroll
                for (int u = 0; u < 16; ++u) c[u] = csrp[e + u];
                uint4 x[16];
                #pragma unroll
                for (int u = 0; u < 16; ++u) x[u] = X4[(size_t)c[u].x * 16 + li];
                #pragma unroll
                for (int u = 0; u < 16; ++u) {
                    float w = __int_as_float(c[u].y);
                    a[0] += w * bflo(x[u].x); a[1] += w * bfhi(x[u].x);
                    a[2] += w * bflo(x[u].y); a[3] += w * bfhi(x[u].y);
                    a[4] += w * bflo(x[u].z); a[5] += w * bfhi(x[u].z);
                    a[6] += w * bflo(x[u].w); a[7] += w * bfhi(x[u].w);
                }
            }
            for (; e + 8 <= rr.y; e += 8) {
                int2 c[8];
                #pragma unroll
                for (int u = 0; u < 8; ++u) c[u] = csrp[e + u];
                uint4 x[8];
                #pragma unroll
                for (int u = 0; u < 8; ++u) x[u] = X4[(size_t)c[u].x * 16 + li];
                #pragma unroll
                for (int u = 0; u < 8; ++u) {
                    float w = __int_as_float(c[u].y);
                    a[0] += w * bflo(x[u].x); a[1] += w * bfhi(x[u].x);
                    a[2] += w * bflo(x[u].y); a[3] += w * bfhi(x[u].y);
                    a[4] += w * bflo(x[u].z); a[5] += w * bfhi(x[u].z);
                    a[6] += w * bflo(x[u].w); a[7] += w * bfhi(x[u].w);
                }
            }
            for (; e < rr.y; ++e) {
                int2 c = csrp[e];
                float w = __int_as_float(c.y);
                uint4 x = X4[(size_t)c.x * 16 + li];
                a[0] += w * bflo(x.x); a[1] += w * bfhi(x.x);
                a[2] += w * bflo(x.y); a[3] += w * bfhi(x.y);
                a[4] += w * bflo(x.z); a[5] += w * bfhi(x.z);
                a[6] += w * bflo(x.w); a[7] += w * bfhi(x.w);
            }
        }
        uint4 o;
        o.x = pack2bf(a[0], a[1]);
        o.y = pack2bf(a[2], a[3]);
        o.z = pack2bf(a[4], a[5]);
        o.w = pack2bf(a[6], a[7]);
        Ys[qw][li] = o;
    }
    __syncthreads();

    // ---- MFMA phase ----
    int w = tid >> 6, l = tid & 63;
    int rg = w & 1;
    int ntb = (w >> 1) * 2;
    f32x4 acc[2];
    acc[0] = (f32x4){0.f, 0.f, 0.f, 0.f};
    acc[1] = (f32x4){0.f, 0.f, 0.f, 0.f};
    const short8* __restrict__ bfr = (const short8*)Bswz;
    #pragma unroll
    for (int kf = 0; kf < 4; ++kf) {
        short8 a = *((const short8*)&Ys[rg * 16 + (l & 15)][kf * 4 + (l >> 4)]);
        #pragma unroll
        for (int t = 0; t < 2; ++t) {
            short8 b = bfr[(kf * 8 + ntb + t) * 64 + l];
            acc[t] = __builtin_amdgcn_mfma_f32_16x16x32_bf16(a, b, acc[t], 0, 0, 0);
        }
    }
    int pidx16 = blockIdx.x * 2 + rg;
    int lrbase = rg * 16 + (l >> 4) * 4;
    int cbase = l & 15;
    #pragma unroll
    for (int t = 0; t < 2; ++t) {
        int nt = ntb + t;
        uint2 bb = btf[(size_t)(pidx16 * 8 + nt) * 64 + l];
        float bi[4] = {bflo(bb.x), bfhi(bb.x), bflo(bb.y), bfhi(bb.y)};
        int col = nt * 16 + cbase;
        #pragma unroll
        for (int i = 0; i < 4; ++i) {
            int jp = blockIdx.x * 32 + lrbase + i;
            if (jp < n) {
                float v = acc[t][i] + bi[i];
                Xout[(size_t)jp * 128 + col] = f2bf(v > 0.f ? v : 0.f);
            }
        }
    }
}

// ---------------- final: normalize rows + H @ Vw^T (perm-space input) ----------------

__global__ __launch_bounds__(256) void final_out(const u16* __restrict__ Xb,
                                                 const int* __restrict__ perm,
                                                 const float* __restrict__ Vw,
                                                 float* __restrict__ out, int n) {
    __shared__ float Vs[40][132];
    int tid = threadIdx.x;
    int jb = blockIdx.x * 64;
    for (int i = tid; i < 40 * 128; i += 256) {
        int c = i >> 7, k = i & 127;
        Vs[c][(k >> 5) * 33 + (k & 31)] = Vw[i];
    }
    int g = tid >> 2, q = tid & 3;
    int jp = jb + g;
    float xs[32];
    float ssq = 0.f;
    if (jp < n) {
        const uint4* X4 = (const uint4*)(Xb + (size_t)jp * 128) + q * 4;
        #pragma unroll
        for (int v = 0; v < 4; ++v) {
            uint4 u = X4[v];
            xs[v * 8 + 0] = bflo(u.x); xs[v * 8 + 1] = bfhi(u.x);
            xs[v * 8 + 2] = bflo(u.y); xs[v * 8 + 3] = bfhi(u.y);
            xs[v * 8 + 4] = bflo(u.z); xs[v * 8 + 5] = bfhi(u.z);
            xs[v * 8 + 6] = bflo(u.w); xs[v * 8 + 7] = bfhi(u.w);
        }
        #pragma unroll
        for (int m = 0; m < 32; ++m) ssq += xs[m] * xs[m];
    } else {
        #pragma unroll
        for (int m = 0; m < 32; ++m) xs[m] = 0.f;
    }
    ssq += __shfl_xor(ssq, 1, 64);
    ssq += __shfl_xor(ssq, 2, 64);
    float inv = 1.f / fmaxf(sqrtf(ssq), 1e-12f);
    #pragma unroll
    for (int m = 0; m < 32; ++m) xs[m] *= inv;
    __syncthreads();
    float pacc[10];
    #pragma unroll
    for (int cc = 0; cc < 10; ++cc) pacc[cc] = 0.f;
    #pragma unroll 1
    for (int c = 0; c < 40; ++c) {
        const float* vrow = &Vs[c][q * 33];
        float acc = 0.f;
        #pragma unroll
        for (int m = 0; m < 32; ++m) acc += xs[m] * vrow[m];
        acc += __shfl_xor(acc, 1, 64);
        acc += __shfl_xor(acc, 2, 64);
        if ((c & 3) == q) pacc[c >> 2] = acc;
    }
    if (jp < n) {
        int j = perm[jp];
        #pragma unroll
        for (int cc = 0; cc < 10; ++cc) {
            int c = cc * 4 + q;
            out[(size_t)j * 40 + c] = pacc[cc];
        }
    }
}

// ---------------- launch ----------------

extern "C" void kernel_launch(void* const* d_in, const int* in_sizes, int n_in,
                              void* d_out, int out_size, void* d_ws, size_t ws_size,
                              hipStream_t stream) {
    const float* F    = (const float*)d_in[0];   // (256, 50000)
    const float* W    = (const float*)d_in[1];   // (128, 128)
    const float* Om   = (const float*)d_in[2];   // (128, 256)
    const float* Vw   = (const float*)d_in[3];   // (40, 128)
    const float* X0   = (const float*)d_in[4];   // (128, 50000)
    const float* ew   = (const float*)d_in[5];   // (E,)
    const int*   esrc = (const int*)d_in[6];
    const int*   edst = (const int*)d_in[7];
    float* out = (float*)d_out;
    (void)in_sizes; (void)n_in; (void)out_size; (void)ws_size;

    char* ws = (char*)d_ws;
    size_t off = 0;
    auto alloc = [&](size_t bytes) -> void* {
        void* p = ws + off;
        off = (off + bytes + 255) & ~(size_t)255;
        return p;
    };
    float* buf0    = (float*)alloc((size_t)N_NODES * 4);
    float* buf1    = (float*)alloc((size_t)N_NODES * 4);
    float* ss      = (float*)alloc(64 * 4);
    int*   deg     = (int*)  alloc((size_t)(N_NODES + 1) * 4);
    int*   offs_d  = (int*)  alloc((size_t)(N_NODES + 1) * 4);
    int*   cur_d   = (int*)  alloc((size_t)N_NODES * 4);
    int*   bsum    = (int*)  alloc(512 * 4);
    int*   bbase   = (int*)  alloc(512 * 4);
    int*   bh      = (int*)  alloc((size_t)(256 * NBK + 1) * 4);
    int*   obase   = (int*)  alloc((size_t)(256 * NBK + 1) * 4);
    int*   ocur    = (int*)  alloc((size_t)(256 * NBK + 1) * 4);
    int*   perm    = (int*)  alloc((size_t)N_NODES * 4);
    int*   invp    = (int*)  alloc((size_t)N_NODES * 4);
    int2*  rowrng  = (int2*) alloc((size_t)N_NODES * 8);
    int2*  csrp    = (int2*) alloc((size_t)N_EDGES * 8);   // by-dst, src in perm space
    u16*   Bswz    = (u16*)  alloc(128 * 128 * 2);
    u16*   Ofrg    = (u16*)  alloc(128 * 256 * 2);
    u16*   btr     = (u16*)  alloc((size_t)N_NODES * 128 * 2);    // bias (perm-space rows)
    uint2* btf     = (uint2*)alloc((size_t)3200 * 512 * 8);       // bias C-frag
    u16*   Utb     = (u16*)  alloc((size_t)N_NODES * 128 * 2);    // perm-space rows
    u16*   Xa      = (u16*)  alloc((size_t)N_NODES * 128 * 2);
    u16*   Xb      = (u16*)  alloc((size_t)N_NODES * 128 * 2);

    hipMemsetAsync(deg, 0, (size_t)(N_NODES + 1) * 4, stream);

    const int n1 = N_NODES + 1;
    const int nb = (n1 + SBLK - 1) / SBLK;   // 196 <= 256

    // ---- degree count + offsets ----
    count_deg<<<(N_EDGES + 255) / 256, 256, 0, stream>>>(edst, deg, N_EDGES);
    scan_local<<<nb, SBLK, 0, stream>>>(deg, offs_d, bsum, n1);
    scan_bsum<<<1, SBLK, 0, stream>>>(bsum, bbase, nb);
    scan_add<<<nb, SBLK, 0, stream>>>(offs_d, cur_d, bbase, n1);

    // ---- degree-sorted permutation (contention-free block-local counting sort) ----
    bhist<<<NBK, 256, 0, stream>>>(deg, bh, N_NODES);
    {
        const int sn1 = 256 * NBK + 1;
        const int snb = (sn1 + SBLK - 1) / SBLK;   // 197 <= 256
        scan_local<<<snb, SBLK, 0, stream>>>(bh, obase, bsum, sn1);
        scan_bsum<<<1, SBLK, 0, stream>>>(bsum, bbase, snb);
        scan_add<<<snb, SBLK, 0, stream>>>(obase, ocur, bbase, sn1);
    }
    bscatter<<<NBK, 256, 0, stream>>>(deg, obase, perm, N_NODES);
    build_invperm<<<(N_NODES + 255) / 256, 256, 0, stream>>>(perm, invp, N_NODES);

    // ---- CSR fill directly in perm space + row ranges ----
    fill_csr_perm<<<(N_EDGES + 255) / 256, 256, 0, stream>>>(
        esrc, edst, ew, invp, cur_d, csrp, N_EDGES);
    build_rowrange<<<(N_NODES + 255) / 256, 256, 0, stream>>>(offs_d, perm, rowrng, N_NODES);

    // ---- power iteration on A^T (discrete launches; coop grid.sync is 20x slower) ----
    fill_pow<<<(N_NODES + 255) / 256, 256, 0, stream>>>(
        buf0, ss, N_NODES, 1.f / sqrtf((float)N_NODES));
    float* bufs[2] = {buf0, buf1};
    for (int it = 0; it <= PWR_ITERS; ++it) {
        matvec_norm<<<(8 * N_NODES + 255) / 256, 256, 0, stream>>>(
            rowrng, csrp, bufs[it & 1], ss + it,
            bufs[(it + 1) & 1], ss + it + 1, N_NODES);
    }

    // ---- project W (rho^2 = ss[PWR_ITERS+1]) -> Bswz fragments ----
    project_w<<<128, 128, 0, stream>>>(W, ss + PWR_ITERS + 1, Bswz);

    // ---- b = (Omega_1 @ U) @ A : all perm-space ----
    reorder_om<<<128, 256, 0, stream>>>(Om, Ofrg);
    gemm_u_mfma<<<(N_NODES + 63) / 64, 256, 0, stream>>>(F, Ofrg, invp, Utb, N_NODES);
    spmm_bf16<<<(N_NODES + 15) / 16, 256, 0, stream>>>(rowrng, csrp, Utb, btr, N_NODES);
    reorder_bt<<<dim3((N_NODES + 15) / 16, 2), 256, 0, stream>>>(btr, btf, N_NODES);

    // ---- fixed point (fused, perm-space X) ----
    transpose_x0_bf16<<<dim3((N_NODES + 31) / 32, 4), dim3(32, 8), 0, stream>>>(X0, invp, Xa, N_NODES);
    u16* xb2[2] = {Xa, Xb};
    for (int it = 0; it < FP_ITERS; ++it) {
        fused_fp<<<(N_NODES + 31) / 32, 512, 0, stream>>>(
            rowrng, csrp, xb2[it & 1], Bswz, btf, xb2[(it + 1) & 1], N_NODES);
    }

    // ---- output ----
    final_out<<<(N_NODES + 63) / 64, 256, 0, stream>>>(xb2[FP_ITERS & 1], perm, Vw, out, N_NODES);
}